// Round 7
// baseline (480.216 us; speedup 1.0000x reference)
//
#include <hip/hip_runtime.h>
#include <math.h>

// Problem constants
#define BATCH 2
#define SEQ   2048
#define DM    768
#define NHD   12
#define NL    2
#define DFF   3072
#define DH    64
#define HW    256            // WIN // 2
#define MR    (BATCH*SEQ)    // 4096
#define EPSF  1e-5f
#define SCALE 0.125f         // DH^-0.5
#define QKVS  2304           // fused qkv activation row stride

typedef __attribute__((ext_vector_type(8))) __bf16 bf16x8;
typedef __attribute__((ext_vector_type(4))) float  f32x4;

__device__ __forceinline__ ushort f2bu(float f) {
    union { __bf16 h; ushort u; } c;
    c.h = (__bf16)f;
    return c.u;
}
__device__ __forceinline__ float bu2f(ushort u) {
    union { uint u; float f; } c;
    c.u = ((uint)u) << 16;
    return c.f;
}

// async global->LDS, 16B per lane. LDS dest must be linear: uniform base +
// lane*16 within each wave (learn_hip m104).
__device__ __forceinline__ void gload16(const ushort* g, ushort* l) {
    __builtin_amdgcn_global_load_lds(
        (const __attribute__((address_space(1))) void*)g,
        (__attribute__((address_space(3))) void*)l, 16, 0, 0);
}

// XCD-aware chunked block remap (T1): consecutive logical tiles (which share
// operand panels) land on the SAME XCD's L2. Requires nwg % 8 == 0 (grids:
// 1152/768). Pure permutation.
__device__ __forceinline__ void xcd_swz(int& bx, int& by, int& bz) {
    const int gx = gridDim.x, gy = gridDim.y;
    const int nwg = gx * gy * gridDim.z;
    int lin = bx + gx * (by + gy * bz);
    lin = (lin & 7) * (nwg >> 3) + (lin >> 3);
    bx = lin % gx;
    int rest = lin / gx;
    by = rest % gy;
    bz = rest / gy;
}

// ---------------------------------------------------------------------------
// fp32 -> bf16 cast, 4 elems/thread (n divisible by 1024)
// ---------------------------------------------------------------------------
__global__ __launch_bounds__(256) void cvt(const float* __restrict__ in,
                                           ushort* __restrict__ out, int n)
{
    int i = (blockIdx.x * 256 + threadIdx.x) * 4;
    if (i >= n) return;
    float4 v = *(const float4*)(in + i);
    ushort4 o;
    o.x = f2bu(v.x); o.y = f2bu(v.y); o.z = f2bu(v.z); o.w = f2bu(v.w);
    *(ushort4*)(out + i) = o;
}

// ---------------------------------------------------------------------------
// MFMA GEMM, 128x128 tile, BK=32, 4 waves (2x2), wave = 64x64 via 4x4
// fragments. Prefetch double-buffer (issue next K-step's global_load_lds
// before this step's ds_read+MFMA; one barrier per K-step).
// Fragment layouts (learn_hip m89/m91, HW-verified):
//   A-frag: A[m = lane&15][k = (lane>>4)*8 + j]
//   B-frag: W[n = lane&15][k = (lane>>4)*8 + j]
//   C/D:    col(n) = lane&15, row(m) = (lane>>4)*4 + reg
// ---------------------------------------------------------------------------
__global__ __launch_bounds__(256) void gemm128(
    const ushort* __restrict__ A, const ushort* __restrict__ W,
    const float* __restrict__ bias, ushort* __restrict__ C,
    int M, int N, int K, int relu)
{
    __shared__ ushort As[2][128 * 32];
    __shared__ ushort Ws[2][128 * 32];

    int bxi = blockIdx.x, byi = blockIdx.y, bzi = blockIdx.z;
    xcd_swz(bxi, byi, bzi);

    const int t  = threadIdx.x;
    const int bm = byi * 128;
    const int bn = bxi * 128;

    const int w    = t >> 6;
    const int lane = t & 63;
    const int quad = lane >> 4;
    const int lrow = lane & 15;
    const int wm   = (w >> 1) * 64;
    const int wn   = (w & 1) * 64;

    const int srow = t >> 2;          // 0..63 (e=0), +64 for e=1
    const int scol = (t & 3) * 8;
    const ushort* ag = A + (size_t)(bm + srow) * K + scol;
    const ushort* wg = W + (size_t)(bn + srow) * K + scol;

    f32x4 acc[4][4] = {};

    gload16(ag,                  &As[0][t * 8]);
    gload16(ag + (size_t)64 * K, &As[0][2048 + t * 8]);
    gload16(wg,                  &Ws[0][t * 8]);
    gload16(wg + (size_t)64 * K, &Ws[0][2048 + t * 8]);
    __syncthreads();

    int cur = 0;
    for (int k0 = 0; k0 < K; k0 += 32) {
        const int nxt = cur ^ 1;
        if (k0 + 32 < K) {
            gload16(ag + k0 + 32,                  &As[nxt][t * 8]);
            gload16(ag + (size_t)64 * K + k0 + 32, &As[nxt][2048 + t * 8]);
            gload16(wg + k0 + 32,                  &Ws[nxt][t * 8]);
            gload16(wg + (size_t)64 * K + k0 + 32, &Ws[nxt][2048 + t * 8]);
        }

        bf16x8 af[4], bfr[4];
#pragma unroll
        for (int i = 0; i < 4; ++i)
            af[i] = *(const bf16x8*)&As[cur][(wm + i * 16 + lrow) * 32 + quad * 8];
#pragma unroll
        for (int j = 0; j < 4; ++j)
            bfr[j] = *(const bf16x8*)&Ws[cur][(wn + j * 16 + lrow) * 32 + quad * 8];

#pragma unroll
        for (int i = 0; i < 4; ++i)
#pragma unroll
            for (int j = 0; j < 4; ++j)
                acc[i][j] = __builtin_amdgcn_mfma_f32_16x16x32_bf16(
                    af[i], bfr[j], acc[i][j], 0, 0, 0);
        __syncthreads();
        cur = nxt;
    }

#pragma unroll
    for (int j = 0; j < 4; ++j) {
        const int col = bn + wn + j * 16 + lrow;
        const float bv = bias[col];
#pragma unroll
        for (int i = 0; i < 4; ++i) {
            const int rb = bm + wm + i * 16 + quad * 4;
#pragma unroll
            for (int r = 0; r < 4; ++r) {
                float vv = acc[i][j][r] + bv;
                if (relu) vv = fmaxf(vv, 0.f);
                C[(size_t)(rb + r) * N + col] = f2bu(vv);
            }
        }
    }
}

// ---------------------------------------------------------------------------
// MFMA GEMM, BM=64 x BN=128, BK=32, 4 waves (2x2), wave = 32x64 via 2x4
// fragments. Prefetch double-buffer. Optional split-K: z = K-chunk; if
// gridDim.z > 1, write fp32 partials to part[z*M*N + ...]; else bf16 + bias
// (+relu). Kc = chunk length, ldk = full-K row stride.
// ---------------------------------------------------------------------------
__global__ __launch_bounds__(256) void gemm64(
    const ushort* __restrict__ A, const ushort* __restrict__ W,
    const float* __restrict__ bias, ushort* __restrict__ C,
    float* __restrict__ part, int M, int N, int Kc, int ldk, int relu)
{
    __shared__ ushort As[2][64 * 32];
    __shared__ ushort Ws[2][128 * 32];

    int bxi = blockIdx.x, byi = blockIdx.y, bzi = blockIdx.z;
    xcd_swz(bxi, byi, bzi);

    const int t  = threadIdx.x;
    const int bm = byi * 64;
    const int bn = bxi * 128;
    const int z  = bzi;
    const int kbase = z * Kc;

    const int w    = t >> 6;
    const int lane = t & 63;
    const int quad = lane >> 4;
    const int lrow = lane & 15;
    const int wm   = (w >> 1) * 32;
    const int wn   = (w & 1) * 64;

    const int srow = t >> 2;          // 0..63
    const int scol = (t & 3) * 8;
    const ushort* ag = A + (size_t)(bm + srow) * ldk + kbase + scol;
    const ushort* wg = W + (size_t)(bn + srow) * ldk + kbase + scol;

    f32x4 acc[2][4] = {};

    gload16(ag,                    &As[0][t * 8]);
    gload16(wg,                    &Ws[0][t * 8]);
    gload16(wg + (size_t)64 * ldk, &Ws[0][2048 + t * 8]);
    __syncthreads();

    int cur = 0;
    for (int k0 = 0; k0 < Kc; k0 += 32) {
        const int nxt = cur ^ 1;
        if (k0 + 32 < Kc) {
            gload16(ag + k0 + 32,                    &As[nxt][t * 8]);
            gload16(wg + k0 + 32,                    &Ws[nxt][t * 8]);
            gload16(wg + (size_t)64 * ldk + k0 + 32, &Ws[nxt][2048 + t * 8]);
        }

        bf16x8 af[2], bfr[4];
#pragma unroll
        for (int i = 0; i < 2; ++i)
            af[i] = *(const bf16x8*)&As[cur][(wm + i * 16 + lrow) * 32 + quad * 8];
#pragma unroll
        for (int j = 0; j < 4; ++j)
            bfr[j] = *(const bf16x8*)&Ws[cur][(wn + j * 16 + lrow) * 32 + quad * 8];

#pragma unroll
        for (int i = 0; i < 2; ++i)
#pragma unroll
            for (int j = 0; j < 4; ++j)
                acc[i][j] = __builtin_amdgcn_mfma_f32_16x16x32_bf16(
                    af[i], bfr[j], acc[i][j], 0, 0, 0);
        __syncthreads();
        cur = nxt;
    }

    if (gridDim.z > 1) {
        float* po = part + (size_t)z * M * N;
#pragma unroll
        for (int j = 0; j < 4; ++j) {
            const int col = bn + wn + j * 16 + lrow;
#pragma unroll
            for (int i = 0; i < 2; ++i) {
                const int rb = bm + wm + i * 16 + quad * 4;
#pragma unroll
                for (int r = 0; r < 4; ++r)
                    po[(size_t)(rb + r) * N + col] = acc[i][j][r];
            }
        }
    } else {
#pragma unroll
        for (int j = 0; j < 4; ++j) {
            const int col = bn + wn + j * 16 + lrow;
            const float bv = bias[col];
#pragma unroll
            for (int i = 0; i < 2; ++i) {
                const int rb = bm + wm + i * 16 + quad * 4;
#pragma unroll
                for (int r = 0; r < 4; ++r) {
                    float vv = acc[i][j][r] + bv;
                    if (relu) vv = fmaxf(vv, 0.f);
                    C[(size_t)(rb + r) * N + col] = f2bu(vv);
                }
            }
        }
    }
}

// ---------------------------------------------------------------------------
// Banded attention, flash single pass, double-buffered, SWAPPED QK^T (T12
// prereq): compute mfma(K, Q) so D[m=key][n=q] -> each lane holds 16 keys of
// ONE q-row (q = qrow+lrow). Softmax row-reduce = reg-local + 2 shfl_xor
// (quads). P stored as 4x ushort4 at sc[q][kt*16+quad*4]; PA read-back layout
// identical to before. Rescale factors cross layouts via __shfl(f, quad*4+r).
// Defer-max (T13, THR=8): skip O-rescale when no row's max grew (wave-uniform
// __all). Mask hoisting: chunks c in [1,7] with j-range in-bounds are fully
// unmasked (wave-uniform 'full' flag).
// ---------------------------------------------------------------------------
#define QT  64
#define NCH 9    // union window 64+512 = 576 keys
#define KP  72   // LDS pitch in bf16 (144 B rows: 16B-aligned, 2-way max)

__global__ __launch_bounds__(256) void attn(
    const ushort* __restrict__ q, const ushort* __restrict__ k,
    const ushort* __restrict__ v, ushort* __restrict__ o)
{
    __shared__ ushort kv[2][64][KP];   // K chunk [key][dh]
    __shared__ ushort vt[2][64][KP];   // V^T chunk [dh][key], XOR-swizzled
    __shared__ ushort sc[QT][KP];      // Q staging, then per-chunk P tiles

    int bxi = blockIdx.x, byi = blockIdx.y, bzi = blockIdx.z;
    xcd_swz(bxi, byi, bzi);            // seq-neighbors share KV -> same XCD

    const int t    = threadIdx.x;
    const int i0   = bxi * QT;
    const int h    = byi;
    const int b    = bzi;
    const size_t ibase = (size_t)b * SEQ * QKVS + (size_t)h * DH;  // q/k/v
    const size_t obase = (size_t)b * SEQ * DM   + (size_t)h * DH;  // o

    const int w    = t >> 6;
    const int lane = t & 63;
    const int quad = lane >> 4;
    const int lrow = lane & 15;
    const int qrow = w * 16;            // wave's 16 query rows

    const int jstart = i0 - HW;

    const int sjj[2] = { t >> 3, (t + 256) >> 3 };
    const int sd0 = (t & 7) * 8;

    // ---- stage Q into sc + load chunk 0 into regs -------------------------
#pragma unroll
    for (int e = 0; e < 2; ++e) {
        int idx = t + 256 * e;
        int qi = idx >> 3, d0 = (idx & 7) * 8;
        uint4 raw = *(const uint4*)(q + ibase + (size_t)(i0 + qi) * QKVS + d0);
        *(uint4*)&sc[qi][d0] = raw;
    }
    uint4 kr[2], vr[2];
#pragma unroll
    for (int e = 0; e < 2; ++e) {
        int j = jstart + sjj[e];
        kr[e] = make_uint4(0, 0, 0, 0);
        vr[e] = make_uint4(0, 0, 0, 0);
        if (j >= 0 && j < SEQ) {
            kr[e] = *(const uint4*)(k + ibase + (size_t)j * QKVS + sd0);
            vr[e] = *(const uint4*)(v + ibase + (size_t)j * QKVS + sd0);
        }
    }
#pragma unroll
    for (int e = 0; e < 2; ++e) {
        *(uint4*)&kv[0][sjj[e]][sd0] = kr[e];
        const ushort* u = (const ushort*)&vr[e];
#pragma unroll
        for (int x = 0; x < 8; ++x) {
            int dh  = sd0 + x;
            int blk = ((sjj[e] >> 3) ^ (dh >> 3)) & 7;
            vt[0][dh][blk * 8 + (sjj[e] & 7)] = u[x];
        }
    }
    __syncthreads();   // publish sc (Q) and buf0

    // Q fragments as the B-operand (chunk-invariant): B[n=lrow]=Q[qrow+lrow]
    const bf16x8 a0 = *(const bf16x8*)&sc[qrow + lrow][quad * 8];
    const bf16x8 a1 = *(const bf16x8*)&sc[qrow + lrow][32 + quad * 8];

    float m_s = -1e20f, l_s = 0.f;     // per-lane: running max/sum of q-row
    f32x4 oacc[4] = {};

    for (int c = 0; c < NCH; ++c) {
        const int cur = c & 1;
        const int j0  = jstart + c * 64;

        // ---- issue chunk c+1 global loads ---------------------------------
        if (c + 1 < NCH) {
            const int j0n = jstart + (c + 1) * 64;
#pragma unroll
            for (int e = 0; e < 2; ++e) {
                int j = j0n + sjj[e];
                kr[e] = make_uint4(0, 0, 0, 0);
                vr[e] = make_uint4(0, 0, 0, 0);
                if (j >= 0 && j < SEQ) {
                    kr[e] = *(const uint4*)(k + ibase + (size_t)j * QKVS + sd0);
                    vr[e] = *(const uint4*)(v + ibase + (size_t)j * QKVS + sd0);
                }
            }
        }

        // ---- QK^T swapped: D[m=key][n=q]; lane = 16 keys of q=qrow+lrow ---
        const bool full = (c >= 1) && (c <= 7) && (j0 >= 0) && (j0 + 64 <= SEQ);
        float p[4][4];   // [kt][r] = P[q][key = kt*16 + quad*4 + r]
#pragma unroll
        for (int kt = 0; kt < 4; ++kt) {
            const int krow = kt * 16;
            bf16x8 kf0 = *(const bf16x8*)&kv[cur][krow + lrow][quad * 8];
            bf16x8 kf1 = *(const bf16x8*)&kv[cur][krow + lrow][32 + quad * 8];
            f32x4 acc = {};
            acc = __builtin_amdgcn_mfma_f32_16x16x32_bf16(kf0, a0, acc, 0, 0, 0);
            acc = __builtin_amdgcn_mfma_f32_16x16x32_bf16(kf1, a1, acc, 0, 0, 0);
            if (full) {
#pragma unroll
                for (int r = 0; r < 4; ++r) p[kt][r] = acc[r] * SCALE;
            } else {
                const int ig = i0 + qrow + lrow;
#pragma unroll
                for (int r = 0; r < 4; ++r) {
                    const int jg = j0 + krow + quad * 4 + r;
                    bool ok = (jg >= 0) && (jg < SEQ) &&
                              (jg >= ig - HW) && (jg <= ig + HW);
                    p[kt][r] = ok ? acc[r] * SCALE : -1e30f;
                }
            }
        }

        // ---- online softmax: reg-local + cross-quad reduce ----------------
        float cm = p[0][0];
#pragma unroll
        for (int kt = 0; kt < 4; ++kt)
#pragma unroll
            for (int r = 0; r < 4; ++r) cm = fmaxf(cm, p[kt][r]);
        cm = fmaxf(cm, __shfl_xor(cm, 16));
        cm = fmaxf(cm, __shfl_xor(cm, 32));

        const bool resc = !__all(cm <= m_s + 8.f);   // defer-max THR=8
        float f = 1.f;
        if (resc) {
            const float mn = fmaxf(m_s, cm);
            f = __expf(m_s - mn);
            m_s = mn;
        }
        float cs = 0.f;
#pragma unroll
        for (int kt = 0; kt < 4; ++kt)
#pragma unroll
            for (int r = 0; r < 4; ++r) {
                float e = __expf(p[kt][r] - m_s);
                p[kt][r] = e;
                cs += e;
            }
        cs += __shfl_xor(cs, 16);
        cs += __shfl_xor(cs, 32);
        l_s = l_s * f + cs;
        if (resc) {
            float f4[4];
#pragma unroll
            for (int r = 0; r < 4; ++r) f4[r] = __shfl(f, quad * 4 + r);
#pragma unroll
            for (int nt = 0; nt < 4; ++nt)
#pragma unroll
                for (int r = 0; r < 4; ++r) oacc[nt][r] *= f4[r];
        }

        // ---- P to sc: 4x ushort4 at sc[q][kt*16 + quad*4] -----------------
#pragma unroll
        for (int kt = 0; kt < 4; ++kt) {
            ushort4 pw;
            pw.x = f2bu(p[kt][0]);
            pw.y = f2bu(p[kt][1]);
            pw.z = f2bu(p[kt][2]);
            pw.w = f2bu(p[kt][3]);
            *(ushort4*)&sc[qrow + lrow][kt * 16 + quad * 4] = pw;
        }

        // ---- PV: O[q][dh] += P . V^T (A-frag read unchanged) --------------
        bf16x8 pa0 = *(const bf16x8*)&sc[qrow + lrow][quad * 8];
        bf16x8 pa1 = *(const bf16x8*)&sc[qrow + lrow][32 + quad * 8];
#pragma unroll
        for (int nt = 0; nt < 4; ++nt) {
            const int dh  = nt * 16 + lrow;
            const int rsw = (dh >> 3) & 7;
            bf16x8 b0 = *(const bf16x8*)&vt[cur][dh][((quad)     ^ rsw) * 8];
            bf16x8 b1 = *(const bf16x8*)&vt[cur][dh][((quad + 4) ^ rsw) * 8];
            oacc[nt] = __builtin_amdgcn_mfma_f32_16x16x32_bf16(pa0, b0, oacc[nt], 0, 0, 0);
            oacc[nt] = __builtin_amdgcn_mfma_f32_16x16x32_bf16(pa1, b1, oacc[nt], 0, 0, 0);
        }

        // ---- write chunk c+1 regs to buf[cur^1] ---------------------------
        if (c + 1 < NCH) {
            const int nxt = cur ^ 1;
#pragma unroll
            for (int e = 0; e < 2; ++e) {
                *(uint4*)&kv[nxt][sjj[e]][sd0] = kr[e];
                const ushort* u = (const ushort*)&vr[e];
#pragma unroll
                for (int x = 0; x < 8; ++x) {
                    int dh  = sd0 + x;
                    int blk = ((sjj[e] >> 3) ^ (dh >> 3)) & 7;
                    vt[nxt][dh][blk * 8 + (sjj[e] & 7)] = u[x];
                }
            }
        }
        __syncthreads();   // single barrier: publishes buf[nxt], drains buf[cur]
    }

    // ---- write O: col(dh) = nt*16 + lrow, row(q) = qrow + quad*4 + r ------
    const float inv = 1.f / l_s;          // lane's q-row = qrow + lrow
    float inv4[4];
#pragma unroll
    for (int r = 0; r < 4; ++r) inv4[r] = __shfl(inv, quad * 4 + r);
#pragma unroll
    for (int r = 0; r < 4; ++r) {
        const int qi = i0 + qrow + quad * 4 + r;
#pragma unroll
        for (int nt = 0; nt < 4; ++nt)
            o[obase + (size_t)qi * DM + nt * 16 + lrow] = f2bu(oacc[nt][r] * inv4[r]);
    }
}

// ---------------------------------------------------------------------------
// Fused split-K reduce + residual + LayerNorm:
// row = LN(xa + (p0 + p1 + bias)), fp32 end-to-end. 4 rows per 256-thr block.
// Used for both the O-proj tail and the FF2 tail.
// ---------------------------------------------------------------------------
__global__ __launch_bounds__(256) void add_ln_sk(
    const ushort* __restrict__ xa, const float* __restrict__ pp,
    const float* __restrict__ bias, const float* __restrict__ g,
    const float* __restrict__ be,
    ushort* __restrict__ ob, float* __restrict__ of, int fin)
{
    const int r = blockIdx.x * 4 + (threadIdx.x >> 6);
    const int t = threadIdx.x & 63;
    const size_t off = (size_t)r * DM;
    float sv[12];
    float s1 = 0.f, s2 = 0.f;
#pragma unroll
    for (int ii = 0; ii < 12; ++ii) {
        const int c = t + 64 * ii;
        float vv = bu2f(xa[off + c]) + pp[off + c]
                 + pp[(size_t)MR * DM + off + c] + bias[c];
        sv[ii] = vv; s1 += vv; s2 += vv * vv;
    }
#pragma unroll
    for (int o2 = 32; o2; o2 >>= 1) {
        s1 += __shfl_xor(s1, o2);
        s2 += __shfl_xor(s2, o2);
    }
    const float mean = s1 * (1.f / 768.f);
    const float rstd = rsqrtf(s2 * (1.f / 768.f) - mean * mean + EPSF);
#pragma unroll
    for (int ii = 0; ii < 12; ++ii) {
        const int c = t + 64 * ii;
        float v = (sv[ii] - mean) * rstd * g[c] + be[c];
        if (fin) of[off + c] = v;
        else     ob[off + c] = f2bu(v);
    }
}

// ---------------------------------------------------------------------------
// Host orchestration.
// ---------------------------------------------------------------------------
extern "C" void kernel_launch(void* const* d_in, const int* in_sizes, int n_in,
                              void* d_out, int out_size, void* d_ws, size_t ws_size,
                              hipStream_t stream) {
    (void)in_sizes; (void)n_in; (void)out_size; (void)ws_size;
    const float* src = (const float*)d_in[0];
    const float* qw  = (const float*)d_in[1];
    const float* qb  = (const float*)d_in[2];
    const float* kw  = (const float*)d_in[3];
    const float* kb  = (const float*)d_in[4];
    const float* vw  = (const float*)d_in[5];
    const float* vb  = (const float*)d_in[6];
    const float* ow  = (const float*)d_in[7];
    const float* ob  = (const float*)d_in[8];
    const float* w1  = (const float*)d_in[9];
    const float* b1  = (const float*)d_in[10];
    const float* w2  = (const float*)d_in[11];
    const float* b2  = (const float*)d_in[12];
    const float* g1  = (const float*)d_in[13];
    const float* be1 = (const float*)d_in[14];
    const float* g2  = (const float*)d_in[15];
    const float* be2 = (const float*)d_in[16];

    const size_t A    = (size_t)MR * DM;         // 3,145,728
    const size_t WD1  = (size_t)DM * DM;         // 589,824  (per layer)
    const size_t WQKV = (size_t)3 * DM * DM;     // 1,769,472 (per layer)
    const size_t WF1  = (size_t)DFF * DM;        // 2,359,296 (per layer)
    const size_t WF   = (size_t)NL * WF1;        // 4,718,592

    float*  bcat = (float*)d_ws;                 // NL * 2304 fp32
    ushort* p    = (ushort*)(bcat + (size_t)NL * QKVS);
    ushort* qkvwB = p; p += (size_t)NL * WQKV;
    ushort* owB   = p; p += (size_t)NL * WD1;
    ushort* w1B   = p; p += WF;
    ushort* w2B   = p; p += WF;
    ushort* xb    = p; p += A;
    ushort* qkvB  = p; p += 3 * A;
    ushort* oB    = p; p += A;
    ushort* yB    = p; p += A;
    ushort* h1    = p; p += A;
    ushort* ffh   = p;                            // MR*DFF = 12.58M elems

    // FF2 fp32 partials: dead-at-FF2 region qkvB..yB (10A B >= 8A B needed).
    float* partF = (float*)qkvB;
    // O-proj fp32 partials: dead-at-O region ffh (8A B, exact fit); consumed
    // by add_ln_sk BEFORE FF1 overwrites ffh.
    float* partO = (float*)ffh;

    // bias concat (device-to-device, async on stream — graph-capture safe)
    for (int l = 0; l < NL; ++l) {
        hipMemcpyAsync(bcat + (size_t)l * QKVS + 0,    qb + (size_t)l * DM,
                       DM * sizeof(float), hipMemcpyDeviceToDevice, stream);
        hipMemcpyAsync(bcat + (size_t)l * QKVS + DM,   kb + (size_t)l * DM,
                       DM * sizeof(float), hipMemcpyDeviceToDevice, stream);
        hipMemcpyAsync(bcat + (size_t)l * QKVS + 2*DM, vb + (size_t)l * DM,
                       DM * sizeof(float), hipMemcpyDeviceToDevice, stream);
    }

    // weight + src conversion (all sizes divisible by 1024)
    for (int l = 0; l < NL; ++l) {
        cvt<<<(int)(WD1 / 1024), 256, 0, stream>>>(
            qw + (size_t)l * WD1, qkvwB + (size_t)l * WQKV + 0,     (int)WD1);
        cvt<<<(int)(WD1 / 1024), 256, 0, stream>>>(
            kw + (size_t)l * WD1, qkvwB + (size_t)l * WQKV + WD1,   (int)WD1);
        cvt<<<(int)(WD1 / 1024), 256, 0, stream>>>(
            vw + (size_t)l * WD1, qkvwB + (size_t)l * WQKV + 2*WD1, (int)WD1);
    }
    cvt<<<(int)(NL * WD1 / 1024), 256, 0, stream>>>(ow, owB, (int)(NL * WD1));
    cvt<<<(int)(WF / 1024), 256, 0, stream>>>(w1, w1B, (int)WF);
    cvt<<<(int)(WF / 1024), 256, 0, stream>>>(w2, w2B, (int)WF);
    cvt<<<(int)(A  / 1024), 256, 0, stream>>>(src, xb, (int)A);

    const dim3 gQKV(QKVS / 128, MR / 64);       // (18, 64)  1152 blocks
    const dim3 gOp(DM / 128, MR / 64, 2);       // (6, 64, 2) 768 blocks
    const dim3 gF1(DFF / 128, MR / 128);        // (24, 32)  768 blocks
    const dim3 gF2(DM / 128, MR / 64, 2);       // (6, 64, 2) 768 blocks
    const dim3 gA(SEQ / QT, NHD, BATCH);        // (32, 12, 2) 768 blocks

    for (int l = 0; l < NL; ++l) {
        const size_t bD = (size_t)l * DM;
        const size_t bF = (size_t)l * DFF;

        gemm64<<<gQKV, 256, 0, stream>>>(xb, qkvwB + (size_t)l * WQKV,
                                         bcat + (size_t)l * QKVS, qkvB,
                                         nullptr, MR, QKVS, DM, DM, 0);
        attn<<<gA, 256, 0, stream>>>(qkvB, qkvB + DM, qkvB + 2 * DM, oB);
        // O-proj split-K: K=768 -> 2 chunks of 384; fp32 partials in ffh
        gemm64<<<gOp, 256, 0, stream>>>(oB, owB + (size_t)l * WD1, nullptr,
                                        nullptr, partO, MR, DM, DM / 2, DM, 0);
        add_ln_sk<<<MR / 4, 256, 0, stream>>>(xb, partO, ob + bD,
                                              g1 + bD, be1 + bD,
                                              h1, nullptr, 0);
        gemm128<<<gF1, 256, 0, stream>>>(h1, w1B + (size_t)l * WF1, b1 + bF, ffh,
                                         MR, DFF, DM, 1);
        // FF2 split-K: K=3072 -> 2 chunks of 1536; fp32 partials in qkvB
        gemm64<<<gF2, 256, 0, stream>>>(ffh, w2B + (size_t)l * WF1, nullptr,
                                        nullptr, partF, MR, DM, DFF / 2, DFF, 0);
        if (l == NL - 1)
            add_ln_sk<<<MR / 4, 256, 0, stream>>>(h1, partF, b2 + bD,
                                                  g2 + bD, be2 + bD,
                                                  nullptr, (float*)d_out, 1);
        else
            add_ln_sk<<<MR / 4, 256, 0, stream>>>(h1, partF, b2 + bD,
                                                  g2 + bD, be2 + bD,
                                                  xb, nullptr, 0);
    }
}

// Round 8
// 460.673 us; speedup vs baseline: 1.0424x; 1.0424x over previous
//
#include <hip/hip_runtime.h>
#include <math.h>

// Problem constants
#define BATCH 2
#define SEQ   2048
#define DM    768
#define NHD   12
#define NL    2
#define DFF   3072
#define DH    64
#define HW    256            // WIN // 2
#define MR    (BATCH*SEQ)    // 4096
#define EPSF  1e-5f
#define SCALE 0.125f         // DH^-0.5
#define QKVS  2304           // fused qkv activation row stride

typedef __attribute__((ext_vector_type(8))) __bf16 bf16x8;
typedef __attribute__((ext_vector_type(4))) float  f32x4;

__device__ __forceinline__ ushort f2bu(float f) {
    union { __bf16 h; ushort u; } c;
    c.h = (__bf16)f;
    return c.u;
}
__device__ __forceinline__ float bu2f(ushort u) {
    union { uint u; float f; } c;
    c.u = ((uint)u) << 16;
    return c.f;
}

// async global->LDS, 16B per lane. LDS dest must be linear: uniform base +
// lane*16 within each wave (learn_hip m104).
__device__ __forceinline__ void gload16(const ushort* g, ushort* l) {
    __builtin_amdgcn_global_load_lds(
        (const __attribute__((address_space(1))) void*)g,
        (__attribute__((address_space(3))) void*)l, 16, 0, 0);
}

// XCD-aware chunked block remap (T1): consecutive logical tiles (which share
// operand panels) land on the SAME XCD's L2. Requires nwg % 8 == 0 (grids:
// 576/768/1152). Pure permutation.
__device__ __forceinline__ void xcd_swz(int& bx, int& by, int& bz) {
    const int gx = gridDim.x, gy = gridDim.y;
    const int nwg = gx * gy * gridDim.z;
    int lin = bx + gx * (by + gy * bz);
    lin = (lin & 7) * (nwg >> 3) + (lin >> 3);
    bx = lin % gx;
    int rest = lin / gx;
    by = rest % gy;
    bz = rest / gy;
}

// ---------------------------------------------------------------------------
// fp32 -> bf16 cast, 4 elems/thread (n divisible by 1024)
// ---------------------------------------------------------------------------
__global__ __launch_bounds__(256) void cvt(const float* __restrict__ in,
                                           ushort* __restrict__ out, int n)
{
    int i = (blockIdx.x * 256 + threadIdx.x) * 4;
    if (i >= n) return;
    float4 v = *(const float4*)(in + i);
    ushort4 o;
    o.x = f2bu(v.x); o.y = f2bu(v.y); o.z = f2bu(v.z); o.w = f2bu(v.w);
    *(ushort4*)(out + i) = o;
}

// ---------------------------------------------------------------------------
// MFMA GEMM, 128x128 tile, BK=32, 4 waves (2x2), wave = 64x64 via 4x4
// fragments. COUNTED-VMCNT 3-DEEP PIPELINE (T3+T4, m218): 3 LDS buffers;
// per iter: s_waitcnt vmcnt(4) (waits THIS tile's 4 loads; next tile's 4
// stay in flight across the barrier) -> raw s_barrier -> ds_read+MFMA from
// buf[kt%3] -> stage kt+2 into buf[(kt+2)%3]. Never drains to 0 mid-loop.
// Hazards: WAR - stage of buf[(kt-1)%3] happens after iter-kt barrier, which
// all waves reach only after finishing iter-(kt-1) reads. RAW - each wave
// waits its own vmcnt BEFORE the barrier, so staged data is LDS-visible to
// all waves after it. No other vmem ops in the loop -> counts exact.
// Fragment layouts (learn_hip m89/m91, HW-verified):
//   A-frag: A[m = lane&15][k = (lane>>4)*8 + j]
//   B-frag: W[n = lane&15][k = (lane>>4)*8 + j]
//   C/D:    col(n) = lane&15, row(m) = (lane>>4)*4 + reg
// ---------------------------------------------------------------------------
#define STAGE128(bi, kt) do {                                         \
        const int _k0 = (kt) * 32;                                    \
        gload16(ag + _k0,                  &As[bi][t * 8]);           \
        gload16(ag + (size_t)64 * K + _k0, &As[bi][2048 + t * 8]);    \
        gload16(wg + _k0,                  &Ws[bi][t * 8]);           \
        gload16(wg + (size_t)64 * K + _k0, &Ws[bi][2048 + t * 8]);    \
    } while (0)

__global__ __launch_bounds__(256) void gemm128(
    const ushort* __restrict__ A, const ushort* __restrict__ W,
    const float* __restrict__ bias, ushort* __restrict__ C,
    int M, int N, int K, int relu)
{
    __shared__ ushort As[3][128 * 32];
    __shared__ ushort Ws[3][128 * 32];

    int bxi = blockIdx.x, byi = blockIdx.y, bzi = blockIdx.z;
    xcd_swz(bxi, byi, bzi);

    const int t  = threadIdx.x;
    const int bm = byi * 128;
    const int bn = bxi * 128;

    const int w    = t >> 6;
    const int lane = t & 63;
    const int quad = lane >> 4;
    const int lrow = lane & 15;
    const int wm   = (w >> 1) * 64;
    const int wn   = (w & 1) * 64;

    const int srow = t >> 2;          // 0..63 (e=0), +64 for e=1
    const int scol = (t & 3) * 8;
    const ushort* ag = A + (size_t)(bm + srow) * K + scol;
    const ushort* wg = W + (size_t)(bn + srow) * K + scol;

    f32x4 acc[4][4] = {};
    const int NT = K / 32;

    STAGE128(0, 0);
    STAGE128(1, 1);

    for (int kt = 0; kt < NT; ++kt) {
        if (kt + 1 < NT)
            asm volatile("s_waitcnt vmcnt(4)" ::: "memory");
        else
            asm volatile("s_waitcnt vmcnt(0)" ::: "memory");
        __builtin_amdgcn_s_barrier();

        const int cb = kt % 3;
        bf16x8 af[4], bfr[4];
#pragma unroll
        for (int i = 0; i < 4; ++i)
            af[i] = *(const bf16x8*)&As[cb][(wm + i * 16 + lrow) * 32 + quad * 8];
#pragma unroll
        for (int j = 0; j < 4; ++j)
            bfr[j] = *(const bf16x8*)&Ws[cb][(wn + j * 16 + lrow) * 32 + quad * 8];

#pragma unroll
        for (int i = 0; i < 4; ++i)
#pragma unroll
            for (int j = 0; j < 4; ++j)
                acc[i][j] = __builtin_amdgcn_mfma_f32_16x16x32_bf16(
                    af[i], bfr[j], acc[i][j], 0, 0, 0);

        if (kt + 2 < NT) {
            const int sb = (kt + 2) % 3;
            STAGE128(sb, kt + 2);
        }
    }

#pragma unroll
    for (int j = 0; j < 4; ++j) {
        const int col = bn + wn + j * 16 + lrow;
        const float bv = bias[col];
#pragma unroll
        for (int i = 0; i < 4; ++i) {
            const int rb = bm + wm + i * 16 + quad * 4;
#pragma unroll
            for (int r = 0; r < 4; ++r) {
                float vv = acc[i][j][r] + bv;
                if (relu) vv = fmaxf(vv, 0.f);
                C[(size_t)(rb + r) * N + col] = f2bu(vv);
            }
        }
    }
}

// ---------------------------------------------------------------------------
// MFMA GEMM, BM=64 x BN=128, BK=32, 4 waves (2x2), wave = 32x64 via 2x4
// fragments. Same counted-vmcnt 3-deep pipeline (3 loads/step -> vmcnt(3)).
// Optional split-K: z = K-chunk; if gridDim.z > 1, write fp32 partials to
// part[z*M*N + ...]; else bf16 + bias (+relu). Kc = chunk length, ldk =
// full-K row stride.
// ---------------------------------------------------------------------------
#define STAGE64(bi, kt) do {                                            \
        const int _k0 = (kt) * 32;                                      \
        gload16(ag + _k0,                    &As[bi][t * 8]);           \
        gload16(wg + _k0,                    &Ws[bi][t * 8]);           \
        gload16(wg + (size_t)64 * ldk + _k0, &Ws[bi][2048 + t * 8]);    \
    } while (0)

__global__ __launch_bounds__(256) void gemm64(
    const ushort* __restrict__ A, const ushort* __restrict__ W,
    const float* __restrict__ bias, ushort* __restrict__ C,
    float* __restrict__ part, int M, int N, int Kc, int ldk, int relu)
{
    __shared__ ushort As[3][64 * 32];
    __shared__ ushort Ws[3][128 * 32];

    int bxi = blockIdx.x, byi = blockIdx.y, bzi = blockIdx.z;
    xcd_swz(bxi, byi, bzi);

    const int t  = threadIdx.x;
    const int bm = byi * 64;
    const int bn = bxi * 128;
    const int z  = bzi;
    const int kbase = z * Kc;

    const int w    = t >> 6;
    const int lane = t & 63;
    const int quad = lane >> 4;
    const int lrow = lane & 15;
    const int wm   = (w >> 1) * 32;
    const int wn   = (w & 1) * 64;

    const int srow = t >> 2;          // 0..63
    const int scol = (t & 3) * 8;
    const ushort* ag = A + (size_t)(bm + srow) * ldk + kbase + scol;
    const ushort* wg = W + (size_t)(bn + srow) * ldk + kbase + scol;

    f32x4 acc[2][4] = {};
    const int NT = Kc / 32;

    STAGE64(0, 0);
    STAGE64(1, 1);

    for (int kt = 0; kt < NT; ++kt) {
        if (kt + 1 < NT)
            asm volatile("s_waitcnt vmcnt(3)" ::: "memory");
        else
            asm volatile("s_waitcnt vmcnt(0)" ::: "memory");
        __builtin_amdgcn_s_barrier();

        const int cb = kt % 3;
        bf16x8 af[2], bfr[4];
#pragma unroll
        for (int i = 0; i < 2; ++i)
            af[i] = *(const bf16x8*)&As[cb][(wm + i * 16 + lrow) * 32 + quad * 8];
#pragma unroll
        for (int j = 0; j < 4; ++j)
            bfr[j] = *(const bf16x8*)&Ws[cb][(wn + j * 16 + lrow) * 32 + quad * 8];

#pragma unroll
        for (int i = 0; i < 2; ++i)
#pragma unroll
            for (int j = 0; j < 4; ++j)
                acc[i][j] = __builtin_amdgcn_mfma_f32_16x16x32_bf16(
                    af[i], bfr[j], acc[i][j], 0, 0, 0);

        if (kt + 2 < NT) {
            const int sb = (kt + 2) % 3;
            STAGE64(sb, kt + 2);
        }
    }

    if (gridDim.z > 1) {
        float* po = part + (size_t)z * M * N;
#pragma unroll
        for (int j = 0; j < 4; ++j) {
            const int col = bn + wn + j * 16 + lrow;
#pragma unroll
            for (int i = 0; i < 2; ++i) {
                const int rb = bm + wm + i * 16 + quad * 4;
#pragma unroll
                for (int r = 0; r < 4; ++r)
                    po[(size_t)(rb + r) * N + col] = acc[i][j][r];
            }
        }
    } else {
#pragma unroll
        for (int j = 0; j < 4; ++j) {
            const int col = bn + wn + j * 16 + lrow;
            const float bv = bias[col];
#pragma unroll
            for (int i = 0; i < 2; ++i) {
                const int rb = bm + wm + i * 16 + quad * 4;
#pragma unroll
                for (int r = 0; r < 4; ++r) {
                    float vv = acc[i][j][r] + bv;
                    if (relu) vv = fmaxf(vv, 0.f);
                    C[(size_t)(rb + r) * N + col] = f2bu(vv);
                }
            }
        }
    }
}

// ---------------------------------------------------------------------------
// Banded attention, flash single pass, double-buffered, SWAPPED QK^T (T12
// prereq): compute mfma(K, Q) so D[m=key][n=q] -> each lane holds 16 keys of
// ONE q-row (q = qrow+lrow). Softmax row-reduce = reg-local + 2 shfl_xor
// (quads). P stored as 4x ushort4 at sc[q][kt*16+quad*4]; PA read-back layout
// identical to before. Rescale factors cross layouts via __shfl(f, quad*4+r).
// Defer-max (T13, THR=8). Mask hoisting for interior chunks. (Unchanged.)
// ---------------------------------------------------------------------------
#define QT  64
#define NCH 9    // union window 64+512 = 576 keys
#define KP  72   // LDS pitch in bf16 (144 B rows: 16B-aligned, 2-way max)

__global__ __launch_bounds__(256) void attn(
    const ushort* __restrict__ q, const ushort* __restrict__ k,
    const ushort* __restrict__ v, ushort* __restrict__ o)
{
    __shared__ ushort kv[2][64][KP];   // K chunk [key][dh]
    __shared__ ushort vt[2][64][KP];   // V^T chunk [dh][key], XOR-swizzled
    __shared__ ushort sc[QT][KP];      // Q staging, then per-chunk P tiles

    int bxi = blockIdx.x, byi = blockIdx.y, bzi = blockIdx.z;
    xcd_swz(bxi, byi, bzi);            // seq-neighbors share KV -> same XCD

    const int t    = threadIdx.x;
    const int i0   = bxi * QT;
    const int h    = byi;
    const int b    = bzi;
    const size_t ibase = (size_t)b * SEQ * QKVS + (size_t)h * DH;  // q/k/v
    const size_t obase = (size_t)b * SEQ * DM   + (size_t)h * DH;  // o

    const int w    = t >> 6;
    const int lane = t & 63;
    const int quad = lane >> 4;
    const int lrow = lane & 15;
    const int qrow = w * 16;            // wave's 16 query rows

    const int jstart = i0 - HW;

    const int sjj[2] = { t >> 3, (t + 256) >> 3 };
    const int sd0 = (t & 7) * 8;

    // ---- stage Q into sc + load chunk 0 into regs -------------------------
#pragma unroll
    for (int e = 0; e < 2; ++e) {
        int idx = t + 256 * e;
        int qi = idx >> 3, d0 = (idx & 7) * 8;
        uint4 raw = *(const uint4*)(q + ibase + (size_t)(i0 + qi) * QKVS + d0);
        *(uint4*)&sc[qi][d0] = raw;
    }
    uint4 kr[2], vr[2];
#pragma unroll
    for (int e = 0; e < 2; ++e) {
        int j = jstart + sjj[e];
        kr[e] = make_uint4(0, 0, 0, 0);
        vr[e] = make_uint4(0, 0, 0, 0);
        if (j >= 0 && j < SEQ) {
            kr[e] = *(const uint4*)(k + ibase + (size_t)j * QKVS + sd0);
            vr[e] = *(const uint4*)(v + ibase + (size_t)j * QKVS + sd0);
        }
    }
#pragma unroll
    for (int e = 0; e < 2; ++e) {
        *(uint4*)&kv[0][sjj[e]][sd0] = kr[e];
        const ushort* u = (const ushort*)&vr[e];
#pragma unroll
        for (int x = 0; x < 8; ++x) {
            int dh  = sd0 + x;
            int blk = ((sjj[e] >> 3) ^ (dh >> 3)) & 7;
            vt[0][dh][blk * 8 + (sjj[e] & 7)] = u[x];
        }
    }
    __syncthreads();   // publish sc (Q) and buf0

    // Q fragments as the B-operand (chunk-invariant): B[n=lrow]=Q[qrow+lrow]
    const bf16x8 a0 = *(const bf16x8*)&sc[qrow + lrow][quad * 8];
    const bf16x8 a1 = *(const bf16x8*)&sc[qrow + lrow][32 + quad * 8];

    float m_s = -1e20f, l_s = 0.f;     // per-lane: running max/sum of q-row
    f32x4 oacc[4] = {};

    for (int c = 0; c < NCH; ++c) {
        const int cur = c & 1;
        const int j0  = jstart + c * 64;

        // ---- issue chunk c+1 global loads ---------------------------------
        if (c + 1 < NCH) {
            const int j0n = jstart + (c + 1) * 64;
#pragma unroll
            for (int e = 0; e < 2; ++e) {
                int j = j0n + sjj[e];
                kr[e] = make_uint4(0, 0, 0, 0);
                vr[e] = make_uint4(0, 0, 0, 0);
                if (j >= 0 && j < SEQ) {
                    kr[e] = *(const uint4*)(k + ibase + (size_t)j * QKVS + sd0);
                    vr[e] = *(const uint4*)(v + ibase + (size_t)j * QKVS + sd0);
                }
            }
        }

        // ---- QK^T swapped: D[m=key][n=q]; lane = 16 keys of q=qrow+lrow ---
        const bool full = (c >= 1) && (c <= 7) && (j0 >= 0) && (j0 + 64 <= SEQ);
        float p[4][4];   // [kt][r] = P[q][key = kt*16 + quad*4 + r]
#pragma unroll
        for (int kt = 0; kt < 4; ++kt) {
            const int krow = kt * 16;
            bf16x8 kf0 = *(const bf16x8*)&kv[cur][krow + lrow][quad * 8];
            bf16x8 kf1 = *(const bf16x8*)&kv[cur][krow + lrow][32 + quad * 8];
            f32x4 acc = {};
            acc = __builtin_amdgcn_mfma_f32_16x16x32_bf16(kf0, a0, acc, 0, 0, 0);
            acc = __builtin_amdgcn_mfma_f32_16x16x32_bf16(kf1, a1, acc, 0, 0, 0);
            if (full) {
#pragma unroll
                for (int r = 0; r < 4; ++r) p[kt][r] = acc[r] * SCALE;
            } else {
                const int ig = i0 + qrow + lrow;
#pragma unroll
                for (int r = 0; r < 4; ++r) {
                    const int jg = j0 + krow + quad * 4 + r;
                    bool ok = (jg >= 0) && (jg < SEQ) &&
                              (jg >= ig - HW) && (jg <= ig + HW);
                    p[kt][r] = ok ? acc[r] * SCALE : -1e30f;
                }
            }
        }

        // ---- online softmax: reg-local + cross-quad reduce ----------------
        float cm = p[0][0];
#pragma unroll
        for (int kt = 0; kt < 4; ++kt)
#pragma unroll
            for (int r = 0; r < 4; ++r) cm = fmaxf(cm, p[kt][r]);
        cm = fmaxf(cm, __shfl_xor(cm, 16));
        cm = fmaxf(cm, __shfl_xor(cm, 32));

        const bool resc = !__all(cm <= m_s + 8.f);   // defer-max THR=8
        float f = 1.f;
        if (resc) {
            const float mn = fmaxf(m_s, cm);
            f = __expf(m_s - mn);
            m_s = mn;
        }
        float cs = 0.f;
#pragma unroll
        for (int kt = 0; kt < 4; ++kt)
#pragma unroll
            for (int r = 0; r < 4; ++r) {
                float e = __expf(p[kt][r] - m_s);
                p[kt][r] = e;
                cs += e;
            }
        cs += __shfl_xor(cs, 16);
        cs += __shfl_xor(cs, 32);
        l_s = l_s * f + cs;
        if (resc) {
            float f4[4];
#pragma unroll
            for (int r = 0; r < 4; ++r) f4[r] = __shfl(f, quad * 4 + r);
#pragma unroll
            for (int nt = 0; nt < 4; ++nt)
#pragma unroll
                for (int r = 0; r < 4; ++r) oacc[nt][r] *= f4[r];
        }

        // ---- P to sc: 4x ushort4 at sc[q][kt*16 + quad*4] -----------------
#pragma unroll
        for (int kt = 0; kt < 4; ++kt) {
            ushort4 pw;
            pw.x = f2bu(p[kt][0]);
            pw.y = f2bu(p[kt][1]);
            pw.z = f2bu(p[kt][2]);
            pw.w = f2bu(p[kt][3]);
            *(ushort4*)&sc[qrow + lrow][kt * 16 + quad * 4] = pw;
        }

        // ---- PV: O[q][dh] += P . V^T (A-frag read unchanged) --------------
        bf16x8 pa0 = *(const bf16x8*)&sc[qrow + lrow][quad * 8];
        bf16x8 pa1 = *(const bf16x8*)&sc[qrow + lrow][32 + quad * 8];
#pragma unroll
        for (int nt = 0; nt < 4; ++nt) {
            const int dh  = nt * 16 + lrow;
            const int rsw = (dh >> 3) & 7;
            bf16x8 b0 = *(const bf16x8*)&vt[cur][dh][((quad)     ^ rsw) * 8];
            bf16x8 b1 = *(const bf16x8*)&vt[cur][dh][((quad + 4) ^ rsw) * 8];
            oacc[nt] = __builtin_amdgcn_mfma_f32_16x16x32_bf16(pa0, b0, oacc[nt], 0, 0, 0);
            oacc[nt] = __builtin_amdgcn_mfma_f32_16x16x32_bf16(pa1, b1, oacc[nt], 0, 0, 0);
        }

        // ---- write chunk c+1 regs to buf[cur^1] ---------------------------
        if (c + 1 < NCH) {
            const int nxt = cur ^ 1;
#pragma unroll
            for (int e = 0; e < 2; ++e) {
                *(uint4*)&kv[nxt][sjj[e]][sd0] = kr[e];
                const ushort* u = (const ushort*)&vr[e];
#pragma unroll
                for (int x = 0; x < 8; ++x) {
                    int dh  = sd0 + x;
                    int blk = ((sjj[e] >> 3) ^ (dh >> 3)) & 7;
                    vt[nxt][dh][blk * 8 + (sjj[e] & 7)] = u[x];
                }
            }
        }
        __syncthreads();   // single barrier: publishes buf[nxt], drains buf[cur]
    }

    // ---- write O: col(dh) = nt*16 + lrow, row(q) = qrow + quad*4 + r ------
    const float inv = 1.f / l_s;          // lane's q-row = qrow + lrow
    float inv4[4];
#pragma unroll
    for (int r = 0; r < 4; ++r) inv4[r] = __shfl(inv, quad * 4 + r);
#pragma unroll
    for (int r = 0; r < 4; ++r) {
        const int qi = i0 + qrow + quad * 4 + r;
#pragma unroll
        for (int nt = 0; nt < 4; ++nt)
            o[obase + (size_t)qi * DM + nt * 16 + lrow] = f2bu(oacc[nt][r] * inv4[r]);
    }
}

// ---------------------------------------------------------------------------
// Fused split-K reduce + residual + LayerNorm:
// row = LN(xa + (p0 + p1 + bias)), fp32 end-to-end. 4 rows per 256-thr block.
// Used for both the O-proj tail and the FF2 tail.
// ---------------------------------------------------------------------------
__global__ __launch_bounds__(256) void add_ln_sk(
    const ushort* __restrict__ xa, const float* __restrict__ pp,
    const float* __restrict__ bias, const float* __restrict__ g,
    const float* __restrict__ be,
    ushort* __restrict__ ob, float* __restrict__ of, int fin)
{
    const int r = blockIdx.x * 4 + (threadIdx.x >> 6);
    const int t = threadIdx.x & 63;
    const size_t off = (size_t)r * DM;
    float sv[12];
    float s1 = 0.f, s2 = 0.f;
#pragma unroll
    for (int ii = 0; ii < 12; ++ii) {
        const int c = t + 64 * ii;
        float vv = bu2f(xa[off + c]) + pp[off + c]
                 + pp[(size_t)MR * DM + off + c] + bias[c];
        sv[ii] = vv; s1 += vv; s2 += vv * vv;
    }
#pragma unroll
    for (int o2 = 32; o2; o2 >>= 1) {
        s1 += __shfl_xor(s1, o2);
        s2 += __shfl_xor(s2, o2);
    }
    const float mean = s1 * (1.f / 768.f);
    const float rstd = rsqrtf(s2 * (1.f / 768.f) - mean * mean + EPSF);
#pragma unroll
    for (int ii = 0; ii < 12; ++ii) {
        const int c = t + 64 * ii;
        float v = (sv[ii] - mean) * rstd * g[c] + be[c];
        if (fin) of[off + c] = v;
        else     ob[off + c] = f2bu(v);
    }
}

// ---------------------------------------------------------------------------
// Host orchestration.
// ---------------------------------------------------------------------------
extern "C" void kernel_launch(void* const* d_in, const int* in_sizes, int n_in,
                              void* d_out, int out_size, void* d_ws, size_t ws_size,
                              hipStream_t stream) {
    (void)in_sizes; (void)n_in; (void)out_size; (void)ws_size;
    const float* src = (const float*)d_in[0];
    const float* qw  = (const float*)d_in[1];
    const float* qb  = (const float*)d_in[2];
    const float* kw  = (const float*)d_in[3];
    const float* kb  = (const float*)d_in[4];
    const float* vw  = (const float*)d_in[5];
    const float* vb  = (const float*)d_in[6];
    const float* ow  = (const float*)d_in[7];
    const float* ob  = (const float*)d_in[8];
    const float* w1  = (const float*)d_in[9];
    const float* b1  = (const float*)d_in[10];
    const float* w2  = (const float*)d_in[11];
    const float* b2  = (const float*)d_in[12];
    const float* g1  = (const float*)d_in[13];
    const float* be1 = (const float*)d_in[14];
    const float* g2  = (const float*)d_in[15];
    const float* be2 = (const float*)d_in[16];

    const size_t A    = (size_t)MR * DM;         // 3,145,728
    const size_t WD1  = (size_t)DM * DM;         // 589,824  (per layer)
    const size_t WQKV = (size_t)3 * DM * DM;     // 1,769,472 (per layer)
    const size_t WF1  = (size_t)DFF * DM;        // 2,359,296 (per layer)
    const size_t WF   = (size_t)NL * WF1;        // 4,718,592

    float*  bcat = (float*)d_ws;                 // NL * 2304 fp32
    ushort* p    = (ushort*)(bcat + (size_t)NL * QKVS);
    ushort* qkvwB = p; p += (size_t)NL * WQKV;
    ushort* owB   = p; p += (size_t)NL * WD1;
    ushort* w1B   = p; p += WF;
    ushort* w2B   = p; p += WF;
    ushort* xb    = p; p += A;
    ushort* qkvB  = p; p += 3 * A;
    ushort* oB    = p; p += A;
    ushort* yB    = p; p += A;
    ushort* h1    = p; p += A;
    ushort* ffh   = p;                            // MR*DFF = 12.58M elems

    // FF2 fp32 partials: dead-at-FF2 region qkvB..yB (10A B >= 8A B needed).
    float* partF = (float*)qkvB;
    // O-proj fp32 partials: dead-at-O region ffh (8A B, exact fit); consumed
    // by add_ln_sk BEFORE FF1 overwrites ffh.
    float* partO = (float*)ffh;

    // bias concat (device-to-device, async on stream — graph-capture safe)
    for (int l = 0; l < NL; ++l) {
        hipMemcpyAsync(bcat + (size_t)l * QKVS + 0,    qb + (size_t)l * DM,
                       DM * sizeof(float), hipMemcpyDeviceToDevice, stream);
        hipMemcpyAsync(bcat + (size_t)l * QKVS + DM,   kb + (size_t)l * DM,
                       DM * sizeof(float), hipMemcpyDeviceToDevice, stream);
        hipMemcpyAsync(bcat + (size_t)l * QKVS + 2*DM, vb + (size_t)l * DM,
                       DM * sizeof(float), hipMemcpyDeviceToDevice, stream);
    }

    // weight + src conversion (all sizes divisible by 1024)
    for (int l = 0; l < NL; ++l) {
        cvt<<<(int)(WD1 / 1024), 256, 0, stream>>>(
            qw + (size_t)l * WD1, qkvwB + (size_t)l * WQKV + 0,     (int)WD1);
        cvt<<<(int)(WD1 / 1024), 256, 0, stream>>>(
            kw + (size_t)l * WD1, qkvwB + (size_t)l * WQKV + WD1,   (int)WD1);
        cvt<<<(int)(WD1 / 1024), 256, 0, stream>>>(
            vw + (size_t)l * WD1, qkvwB + (size_t)l * WQKV + 2*WD1, (int)WD1);
    }
    cvt<<<(int)(NL * WD1 / 1024), 256, 0, stream>>>(ow, owB, (int)(NL * WD1));
    cvt<<<(int)(WF / 1024), 256, 0, stream>>>(w1, w1B, (int)WF);
    cvt<<<(int)(WF / 1024), 256, 0, stream>>>(w2, w2B, (int)WF);
    cvt<<<(int)(A  / 1024), 256, 0, stream>>>(src, xb, (int)A);

    const dim3 gQKV(QKVS / 128, MR / 128);      // (18, 32)  576 blocks
    const dim3 gOp(DM / 128, MR / 64, 2);       // (6, 64, 2) 768 blocks
    const dim3 gF1(DFF / 128, MR / 128);        // (24, 32)  768 blocks
    const dim3 gF2(DM / 128, MR / 64, 2);       // (6, 64, 2) 768 blocks
    const dim3 gA(SEQ / QT, NHD, BATCH);        // (32, 12, 2) 768 blocks

    for (int l = 0; l < NL; ++l) {
        const size_t bD = (size_t)l * DM;
        const size_t bF = (size_t)l * DFF;

        gemm128<<<gQKV, 256, 0, stream>>>(xb, qkvwB + (size_t)l * WQKV,
                                          bcat + (size_t)l * QKVS, qkvB,
                                          MR, QKVS, DM, 0);
        attn<<<gA, 256, 0, stream>>>(qkvB, qkvB + DM, qkvB + 2 * DM, oB);
        // O-proj split-K: K=768 -> 2 chunks of 384; fp32 partials in ffh
        gemm64<<<gOp, 256, 0, stream>>>(oB, owB + (size_t)l * WD1, nullptr,
                                        nullptr, partO, MR, DM, DM / 2, DM, 0);
        add_ln_sk<<<MR / 4, 256, 0, stream>>>(xb, partO, ob + bD,
                                              g1 + bD, be1 + bD,
                                              h1, nullptr, 0);
        gemm128<<<gF1, 256, 0, stream>>>(h1, w1B + (size_t)l * WF1, b1 + bF, ffh,
                                         MR, DFF, DM, 1);
        // FF2 split-K: K=3072 -> 2 chunks of 1536; fp32 partials in qkvB
        gemm64<<<gF2, 256, 0, stream>>>(ffh, w2B + (size_t)l * WF1, nullptr,
                                        nullptr, partF, MR, DM, DFF / 2, DFF, 0);
        if (l == NL - 1)
            add_ln_sk<<<MR / 4, 256, 0, stream>>>(h1, partF, b2 + bD,
                                                  g2 + bD, be2 + bD,
                                                  nullptr, (float*)d_out, 1);
        else
            add_ln_sk<<<MR / 4, 256, 0, stream>>>(h1, partF, b2 + bD,
                                                  g2 + bD, be2 + bD,
                                                  xb, nullptr, 0);
    }
}

// Round 9
// 460.230 us; speedup vs baseline: 1.0434x; 1.0010x over previous
//
#include <hip/hip_runtime.h>
#include <math.h>

// Problem constants
#define BATCH 2
#define SEQ   2048
#define DM    768
#define NHD   12
#define NL    2
#define DFF   3072
#define DH    64
#define HW    256            // WIN // 2
#define MR    (BATCH*SEQ)    // 4096
#define EPSF  1e-5f
#define SCALE 0.125f         // DH^-0.5
#define QKVS  2304           // fused qkv activation row stride

typedef __attribute__((ext_vector_type(8))) __bf16 bf16x8;
typedef __attribute__((ext_vector_type(4))) float  f32x4;

__device__ __forceinline__ ushort f2bu(float f) {
    union { __bf16 h; ushort u; } c;
    c.h = (__bf16)f;
    return c.u;
}
__device__ __forceinline__ float bu2f(ushort u) {
    union { uint u; float f; } c;
    c.u = ((uint)u) << 16;
    return c.f;
}

// async global->LDS, 16B per lane. LDS dest must be linear: uniform base +
// lane*16 within each wave (learn_hip m104).
__device__ __forceinline__ void gload16(const ushort* g, ushort* l) {
    __builtin_amdgcn_global_load_lds(
        (const __attribute__((address_space(1))) void*)g,
        (__attribute__((address_space(3))) void*)l, 16, 0, 0);
}

// XCD-aware chunked block remap (T1): consecutive logical tiles (which share
// operand panels) land on the SAME XCD's L2. Requires nwg % 8 == 0 (grids:
// 576/768/1152). Pure permutation.
__device__ __forceinline__ void xcd_swz(int& bx, int& by, int& bz) {
    const int gx = gridDim.x, gy = gridDim.y;
    const int nwg = gx * gy * gridDim.z;
    int lin = bx + gx * (by + gy * bz);
    lin = (lin & 7) * (nwg >> 3) + (lin >> 3);
    bx = lin % gx;
    int rest = lin / gx;
    by = rest % gy;
    bz = rest / gy;
}

// ---------------------------------------------------------------------------
// fp32 -> bf16 cast, 4 elems/thread (n divisible by 1024)
// ---------------------------------------------------------------------------
__global__ __launch_bounds__(256) void cvt(const float* __restrict__ in,
                                           ushort* __restrict__ out, int n)
{
    int i = (blockIdx.x * 256 + threadIdx.x) * 4;
    if (i >= n) return;
    float4 v = *(const float4*)(in + i);
    ushort4 o;
    o.x = f2bu(v.x); o.y = f2bu(v.y); o.z = f2bu(v.z); o.w = f2bu(v.w);
    *(ushort4*)(out + i) = o;
}

// ---------------------------------------------------------------------------
// MFMA GEMM, 128x128 tile, BK=32, 4 waves (2x2), wave = 64x64 via 4x4
// fragments. Counted-vmcnt 3-deep pipeline (T3+T4, m218) + LDS XOR-SWIZZLE
// (T2, rule #21: linear gload_lds dest + inverse-swizzled GLOBAL source +
// swizzled ds_read):
//   tile slot layout: row (64B = 4 x 16B slots); store col-block
//   (t&3)^((t>>3)&3) at linear slot t&3  ->  read slot quad^((row>>1)&3).
//   For fixed quad a 16-lane group then covers all 8 four-bank groups
//   (2 lanes each = free) instead of 2 (8-way conflict).
// Fragment layouts (learn_hip m89/m91, HW-verified):
//   A-frag: A[m = lane&15][k = (lane>>4)*8 + j]
//   B-frag: W[n = lane&15][k = (lane>>4)*8 + j]
//   C/D:    col(n) = lane&15, row(m) = (lane>>4)*4 + reg
// ---------------------------------------------------------------------------
#define STAGE128(bi, kt) do {                                         \
        const int _k0 = (kt) * 32;                                    \
        gload16(ag + _k0,                  &As[bi][t * 8]);           \
        gload16(ag + (size_t)64 * K + _k0, &As[bi][2048 + t * 8]);    \
        gload16(wg + _k0,                  &Ws[bi][t * 8]);           \
        gload16(wg + (size_t)64 * K + _k0, &Ws[bi][2048 + t * 8]);    \
    } while (0)

__global__ __launch_bounds__(256) void gemm128(
    const ushort* __restrict__ A, const ushort* __restrict__ W,
    const float* __restrict__ bias, ushort* __restrict__ C,
    int M, int N, int K, int relu)
{
    __shared__ ushort As[3][128 * 32];
    __shared__ ushort Ws[3][128 * 32];

    int bxi = blockIdx.x, byi = blockIdx.y, bzi = blockIdx.z;
    xcd_swz(bxi, byi, bzi);

    const int t  = threadIdx.x;
    const int bm = byi * 128;
    const int bn = bxi * 128;

    const int w    = t >> 6;
    const int lane = t & 63;
    const int quad = lane >> 4;
    const int lrow = lane & 15;
    const int wm   = (w >> 1) * 64;
    const int wn   = (w & 1) * 64;
    const int rx   = (lrow >> 1) & 3;          // read-side XOR (T2)
    const int rq   = (quad ^ rx) * 8;          // swizzled slot offset

    const int srow = t >> 2;                   // 0..63 (e=0), +64 for e=1
    // inverse-swizzled source col-block: (t&3) ^ ((row>>1)&3); row bits 1-2
    // are invariant under +64, so one constant serves both halves.
    const int scol = (((t & 3) ^ ((t >> 3) & 3)) * 8);
    const ushort* ag = A + (size_t)(bm + srow) * K + scol;
    const ushort* wg = W + (size_t)(bn + srow) * K + scol;

    f32x4 acc[4][4] = {};
    const int NT = K / 32;

    STAGE128(0, 0);
    STAGE128(1, 1);

    for (int kt = 0; kt < NT; ++kt) {
        if (kt + 1 < NT)
            asm volatile("s_waitcnt vmcnt(4)" ::: "memory");
        else
            asm volatile("s_waitcnt vmcnt(0)" ::: "memory");
        __builtin_amdgcn_s_barrier();

        const int cb = kt % 3;
        bf16x8 af[4], bfr[4];
#pragma unroll
        for (int i = 0; i < 4; ++i)
            af[i] = *(const bf16x8*)&As[cb][(wm + i * 16 + lrow) * 32 + rq];
#pragma unroll
        for (int j = 0; j < 4; ++j)
            bfr[j] = *(const bf16x8*)&Ws[cb][(wn + j * 16 + lrow) * 32 + rq];

#pragma unroll
        for (int i = 0; i < 4; ++i)
#pragma unroll
            for (int j = 0; j < 4; ++j)
                acc[i][j] = __builtin_amdgcn_mfma_f32_16x16x32_bf16(
                    af[i], bfr[j], acc[i][j], 0, 0, 0);

        if (kt + 2 < NT) {
            const int sb = (kt + 2) % 3;
            STAGE128(sb, kt + 2);
        }
    }

#pragma unroll
    for (int j = 0; j < 4; ++j) {
        const int col = bn + wn + j * 16 + lrow;
        const float bv = bias[col];
#pragma unroll
        for (int i = 0; i < 4; ++i) {
            const int rb = bm + wm + i * 16 + quad * 4;
#pragma unroll
            for (int r = 0; r < 4; ++r) {
                float vv = acc[i][j][r] + bv;
                if (relu) vv = fmaxf(vv, 0.f);
                C[(size_t)(rb + r) * N + col] = f2bu(vv);
            }
        }
    }
}

// ---------------------------------------------------------------------------
// MFMA GEMM, BM=64 x BN=128, BK=32, 4 waves (2x2), wave = 32x64 via 2x4
// fragments. Counted-vmcnt 3-deep pipeline + same T2 XOR swizzle.
// Optional split-K: z = K-chunk; if gridDim.z > 1, write fp32 partials to
// part[z*M*N + ...]; else bf16 + bias (+relu). Kc = chunk length, ldk =
// full-K row stride.
// ---------------------------------------------------------------------------
#define STAGE64(bi, kt) do {                                            \
        const int _k0 = (kt) * 32;                                      \
        gload16(ag + _k0,                    &As[bi][t * 8]);           \
        gload16(wg + _k0,                    &Ws[bi][t * 8]);           \
        gload16(wg + (size_t)64 * ldk + _k0, &Ws[bi][2048 + t * 8]);    \
    } while (0)

__global__ __launch_bounds__(256) void gemm64(
    const ushort* __restrict__ A, const ushort* __restrict__ W,
    const float* __restrict__ bias, ushort* __restrict__ C,
    float* __restrict__ part, int M, int N, int Kc, int ldk, int relu)
{
    __shared__ ushort As[3][64 * 32];
    __shared__ ushort Ws[3][128 * 32];

    int bxi = blockIdx.x, byi = blockIdx.y, bzi = blockIdx.z;
    xcd_swz(bxi, byi, bzi);

    const int t  = threadIdx.x;
    const int bm = byi * 64;
    const int bn = bxi * 128;
    const int z  = bzi;
    const int kbase = z * Kc;

    const int w    = t >> 6;
    const int lane = t & 63;
    const int quad = lane >> 4;
    const int lrow = lane & 15;
    const int wm   = (w >> 1) * 32;
    const int wn   = (w & 1) * 64;
    const int rx   = (lrow >> 1) & 3;          // read-side XOR (T2)
    const int rq   = (quad ^ rx) * 8;

    const int srow = t >> 2;                   // 0..63
    const int scol = (((t & 3) ^ ((t >> 3) & 3)) * 8);
    const ushort* ag = A + (size_t)(bm + srow) * ldk + kbase + scol;
    const ushort* wg = W + (size_t)(bn + srow) * ldk + kbase + scol;

    f32x4 acc[2][4] = {};
    const int NT = Kc / 32;

    STAGE64(0, 0);
    STAGE64(1, 1);

    for (int kt = 0; kt < NT; ++kt) {
        if (kt + 1 < NT)
            asm volatile("s_waitcnt vmcnt(3)" ::: "memory");
        else
            asm volatile("s_waitcnt vmcnt(0)" ::: "memory");
        __builtin_amdgcn_s_barrier();

        const int cb = kt % 3;
        bf16x8 af[2], bfr[4];
#pragma unroll
        for (int i = 0; i < 2; ++i)
            af[i] = *(const bf16x8*)&As[cb][(wm + i * 16 + lrow) * 32 + rq];
#pragma unroll
        for (int j = 0; j < 4; ++j)
            bfr[j] = *(const bf16x8*)&Ws[cb][(wn + j * 16 + lrow) * 32 + rq];

#pragma unroll
        for (int i = 0; i < 2; ++i)
#pragma unroll
            for (int j = 0; j < 4; ++j)
                acc[i][j] = __builtin_amdgcn_mfma_f32_16x16x32_bf16(
                    af[i], bfr[j], acc[i][j], 0, 0, 0);

        if (kt + 2 < NT) {
            const int sb = (kt + 2) % 3;
            STAGE64(sb, kt + 2);
        }
    }

    if (gridDim.z > 1) {
        float* po = part + (size_t)z * M * N;
#pragma unroll
        for (int j = 0; j < 4; ++j) {
            const int col = bn + wn + j * 16 + lrow;
#pragma unroll
            for (int i = 0; i < 2; ++i) {
                const int rb = bm + wm + i * 16 + quad * 4;
#pragma unroll
                for (int r = 0; r < 4; ++r)
                    po[(size_t)(rb + r) * N + col] = acc[i][j][r];
            }
        }
    } else {
#pragma unroll
        for (int j = 0; j < 4; ++j) {
            const int col = bn + wn + j * 16 + lrow;
            const float bv = bias[col];
#pragma unroll
            for (int i = 0; i < 2; ++i) {
                const int rb = bm + wm + i * 16 + quad * 4;
#pragma unroll
                for (int r = 0; r < 4; ++r) {
                    float vv = acc[i][j][r] + bv;
                    if (relu) vv = fmaxf(vv, 0.f);
                    C[(size_t)(rb + r) * N + col] = f2bu(vv);
                }
            }
        }
    }
}

// ---------------------------------------------------------------------------
// Banded attention, flash single pass, double-buffered, SWAPPED QK^T (T12
// prereq): compute mfma(K, Q) so D[m=key][n=q] -> each lane holds 16 keys of
// ONE q-row (q = qrow+lrow). Softmax row-reduce = reg-local + 2 shfl_xor
// (quads). P stored as 4x ushort4 at sc[q][kt*16+quad*4]; PA read-back layout
// identical to before. Rescale factors cross layouts via __shfl(f, quad*4+r).
// Defer-max (T13, THR=8). Mask hoisting for interior chunks. (Unchanged.)
// ---------------------------------------------------------------------------
#define QT  64
#define NCH 9    // union window 64+512 = 576 keys
#define KP  72   // LDS pitch in bf16 (144 B rows: 16B-aligned, 2-way max)

__global__ __launch_bounds__(256) void attn(
    const ushort* __restrict__ q, const ushort* __restrict__ k,
    const ushort* __restrict__ v, ushort* __restrict__ o)
{
    __shared__ ushort kv[2][64][KP];   // K chunk [key][dh]
    __shared__ ushort vt[2][64][KP];   // V^T chunk [dh][key], XOR-swizzled
    __shared__ ushort sc[QT][KP];      // Q staging, then per-chunk P tiles

    int bxi = blockIdx.x, byi = blockIdx.y, bzi = blockIdx.z;
    xcd_swz(bxi, byi, bzi);            // seq-neighbors share KV -> same XCD

    const int t    = threadIdx.x;
    const int i0   = bxi * QT;
    const int h    = byi;
    const int b    = bzi;
    const size_t ibase = (size_t)b * SEQ * QKVS + (size_t)h * DH;  // q/k/v
    const size_t obase = (size_t)b * SEQ * DM   + (size_t)h * DH;  // o

    const int w    = t >> 6;
    const int lane = t & 63;
    const int quad = lane >> 4;
    const int lrow = lane & 15;
    const int qrow = w * 16;            // wave's 16 query rows

    const int jstart = i0 - HW;

    const int sjj[2] = { t >> 3, (t + 256) >> 3 };
    const int sd0 = (t & 7) * 8;

    // ---- stage Q into sc + load chunk 0 into regs -------------------------
#pragma unroll
    for (int e = 0; e < 2; ++e) {
        int idx = t + 256 * e;
        int qi = idx >> 3, d0 = (idx & 7) * 8;
        uint4 raw = *(const uint4*)(q + ibase + (size_t)(i0 + qi) * QKVS + d0);
        *(uint4*)&sc[qi][d0] = raw;
    }
    uint4 kr[2], vr[2];
#pragma unroll
    for (int e = 0; e < 2; ++e) {
        int j = jstart + sjj[e];
        kr[e] = make_uint4(0, 0, 0, 0);
        vr[e] = make_uint4(0, 0, 0, 0);
        if (j >= 0 && j < SEQ) {
            kr[e] = *(const uint4*)(k + ibase + (size_t)j * QKVS + sd0);
            vr[e] = *(const uint4*)(v + ibase + (size_t)j * QKVS + sd0);
        }
    }
#pragma unroll
    for (int e = 0; e < 2; ++e) {
        *(uint4*)&kv[0][sjj[e]][sd0] = kr[e];
        const ushort* u = (const ushort*)&vr[e];
#pragma unroll
        for (int x = 0; x < 8; ++x) {
            int dh  = sd0 + x;
            int blk = ((sjj[e] >> 3) ^ (dh >> 3)) & 7;
            vt[0][dh][blk * 8 + (sjj[e] & 7)] = u[x];
        }
    }
    __syncthreads();   // publish sc (Q) and buf0

    // Q fragments as the B-operand (chunk-invariant): B[n=lrow]=Q[qrow+lrow]
    const bf16x8 a0 = *(const bf16x8*)&sc[qrow + lrow][quad * 8];
    const bf16x8 a1 = *(const bf16x8*)&sc[qrow + lrow][32 + quad * 8];

    float m_s = -1e20f, l_s = 0.f;     // per-lane: running max/sum of q-row
    f32x4 oacc[4] = {};

    for (int c = 0; c < NCH; ++c) {
        const int cur = c & 1;
        const int j0  = jstart + c * 64;

        // ---- issue chunk c+1 global loads ---------------------------------
        if (c + 1 < NCH) {
            const int j0n = jstart + (c + 1) * 64;
#pragma unroll
            for (int e = 0; e < 2; ++e) {
                int j = j0n + sjj[e];
                kr[e] = make_uint4(0, 0, 0, 0);
                vr[e] = make_uint4(0, 0, 0, 0);
                if (j >= 0 && j < SEQ) {
                    kr[e] = *(const uint4*)(k + ibase + (size_t)j * QKVS + sd0);
                    vr[e] = *(const uint4*)(v + ibase + (size_t)j * QKVS + sd0);
                }
            }
        }

        // ---- QK^T swapped: D[m=key][n=q]; lane = 16 keys of q=qrow+lrow ---
        const bool full = (c >= 1) && (c <= 7) && (j0 >= 0) && (j0 + 64 <= SEQ);
        float p[4][4];   // [kt][r] = P[q][key = kt*16 + quad*4 + r]
#pragma unroll
        for (int kt = 0; kt < 4; ++kt) {
            const int krow = kt * 16;
            bf16x8 kf0 = *(const bf16x8*)&kv[cur][krow + lrow][quad * 8];
            bf16x8 kf1 = *(const bf16x8*)&kv[cur][krow + lrow][32 + quad * 8];
            f32x4 acc = {};
            acc = __builtin_amdgcn_mfma_f32_16x16x32_bf16(kf0, a0, acc, 0, 0, 0);
            acc = __builtin_amdgcn_mfma_f32_16x16x32_bf16(kf1, a1, acc, 0, 0, 0);
            if (full) {
#pragma unroll
                for (int r = 0; r < 4; ++r) p[kt][r] = acc[r] * SCALE;
            } else {
                const int ig = i0 + qrow + lrow;
#pragma unroll
                for (int r = 0; r < 4; ++r) {
                    const int jg = j0 + krow + quad * 4 + r;
                    bool ok = (jg >= 0) && (jg < SEQ) &&
                              (jg >= ig - HW) && (jg <= ig + HW);
                    p[kt][r] = ok ? acc[r] * SCALE : -1e30f;
                }
            }
        }

        // ---- online softmax: reg-local + cross-quad reduce ----------------
        float cm = p[0][0];
#pragma unroll
        for (int kt = 0; kt < 4; ++kt)
#pragma unroll
            for (int r = 0; r < 4; ++r) cm = fmaxf(cm, p[kt][r]);
        cm = fmaxf(cm, __shfl_xor(cm, 16));
        cm = fmaxf(cm, __shfl_xor(cm, 32));

        const bool resc = !__all(cm <= m_s + 8.f);   // defer-max THR=8
        float f = 1.f;
        if (resc) {
            const float mn = fmaxf(m_s, cm);
            f = __expf(m_s - mn);
            m_s = mn;
        }
        float cs = 0.f;
#pragma unroll
        for (int kt = 0; kt < 4; ++kt)
#pragma unroll
            for (int r = 0; r < 4; ++r) {
                float e = __expf(p[kt][r] - m_s);
                p[kt][r] = e;
                cs += e;
            }
        cs += __shfl_xor(cs, 16);
        cs += __shfl_xor(cs, 32);
        l_s = l_s * f + cs;
        if (resc) {
            float f4[4];
#pragma unroll
            for (int r = 0; r < 4; ++r) f4[r] = __shfl(f, quad * 4 + r);
#pragma unroll
            for (int nt = 0; nt < 4; ++nt)
#pragma unroll
                for (int r = 0; r < 4; ++r) oacc[nt][r] *= f4[r];
        }

        // ---- P to sc: 4x ushort4 at sc[q][kt*16 + quad*4] -----------------
#pragma unroll
        for (int kt = 0; kt < 4; ++kt) {
            ushort4 pw;
            pw.x = f2bu(p[kt][0]);
            pw.y = f2bu(p[kt][1]);
            pw.z = f2bu(p[kt][2]);
            pw.w = f2bu(p[kt][3]);
            *(ushort4*)&sc[qrow + lrow][kt * 16 + quad * 4] = pw;
        }

        // ---- PV: O[q][dh] += P . V^T (A-frag read unchanged) --------------
        bf16x8 pa0 = *(const bf16x8*)&sc[qrow + lrow][quad * 8];
        bf16x8 pa1 = *(const bf16x8*)&sc[qrow + lrow][32 + quad * 8];
#pragma unroll
        for (int nt = 0; nt < 4; ++nt) {
            const int dh  = nt * 16 + lrow;
            const int rsw = (dh >> 3) & 7;
            bf16x8 b0 = *(const bf16x8*)&vt[cur][dh][((quad)     ^ rsw) * 8];
            bf16x8 b1 = *(const bf16x8*)&vt[cur][dh][((quad + 4) ^ rsw) * 8];
            oacc[nt] = __builtin_amdgcn_mfma_f32_16x16x32_bf16(pa0, b0, oacc[nt], 0, 0, 0);
            oacc[nt] = __builtin_amdgcn_mfma_f32_16x16x32_bf16(pa1, b1, oacc[nt], 0, 0, 0);
        }

        // ---- write chunk c+1 regs to buf[cur^1] ---------------------------
        if (c + 1 < NCH) {
            const int nxt = cur ^ 1;
#pragma unroll
            for (int e = 0; e < 2; ++e) {
                *(uint4*)&kv[nxt][sjj[e]][sd0] = kr[e];
                const ushort* u = (const ushort*)&vr[e];
#pragma unroll
                for (int x = 0; x < 8; ++x) {
                    int dh  = sd0 + x;
                    int blk = ((sjj[e] >> 3) ^ (dh >> 3)) & 7;
                    vt[nxt][dh][blk * 8 + (sjj[e] & 7)] = u[x];
                }
            }
        }
        __syncthreads();   // single barrier: publishes buf[nxt], drains buf[cur]
    }

    // ---- write O: col(dh) = nt*16 + lrow, row(q) = qrow + quad*4 + r ------
    const float inv = 1.f / l_s;          // lane's q-row = qrow + lrow
    float inv4[4];
#pragma unroll
    for (int r = 0; r < 4; ++r) inv4[r] = __shfl(inv, quad * 4 + r);
#pragma unroll
    for (int r = 0; r < 4; ++r) {
        const int qi = i0 + qrow + quad * 4 + r;
#pragma unroll
        for (int nt = 0; nt < 4; ++nt)
            o[obase + (size_t)qi * DM + nt * 16 + lrow] = f2bu(oacc[nt][r] * inv4[r]);
    }
}

// ---------------------------------------------------------------------------
// Fused split-K reduce + residual + LayerNorm:
// row = LN(xa + (p0 + p1 + bias)), fp32 end-to-end. 4 rows per 256-thr block.
// Used for both the O-proj tail and the FF2 tail.
// ---------------------------------------------------------------------------
__global__ __launch_bounds__(256) void add_ln_sk(
    const ushort* __restrict__ xa, const float* __restrict__ pp,
    const float* __restrict__ bias, const float* __restrict__ g,
    const float* __restrict__ be,
    ushort* __restrict__ ob, float* __restrict__ of, int fin)
{
    const int r = blockIdx.x * 4 + (threadIdx.x >> 6);
    const int t = threadIdx.x & 63;
    const size_t off = (size_t)r * DM;
    float sv[12];
    float s1 = 0.f, s2 = 0.f;
#pragma unroll
    for (int ii = 0; ii < 12; ++ii) {
        const int c = t + 64 * ii;
        float vv = bu2f(xa[off + c]) + pp[off + c]
                 + pp[(size_t)MR * DM + off + c] + bias[c];
        sv[ii] = vv; s1 += vv; s2 += vv * vv;
    }
#pragma unroll
    for (int o2 = 32; o2; o2 >>= 1) {
        s1 += __shfl_xor(s1, o2);
        s2 += __shfl_xor(s2, o2);
    }
    const float mean = s1 * (1.f / 768.f);
    const float rstd = rsqrtf(s2 * (1.f / 768.f) - mean * mean + EPSF);
#pragma unroll
    for (int ii = 0; ii < 12; ++ii) {
        const int c = t + 64 * ii;
        float v = (sv[ii] - mean) * rstd * g[c] + be[c];
        if (fin) of[off + c] = v;
        else     ob[off + c] = f2bu(v);
    }
}

// ---------------------------------------------------------------------------
// Host orchestration.
// ---------------------------------------------------------------------------
extern "C" void kernel_launch(void* const* d_in, const int* in_sizes, int n_in,
                              void* d_out, int out_size, void* d_ws, size_t ws_size,
                              hipStream_t stream) {
    (void)in_sizes; (void)n_in; (void)out_size; (void)ws_size;
    const float* src = (const float*)d_in[0];
    const float* qw  = (const float*)d_in[1];
    const float* qb  = (const float*)d_in[2];
    const float* kw  = (const float*)d_in[3];
    const float* kb  = (const float*)d_in[4];
    const float* vw  = (const float*)d_in[5];
    const float* vb  = (const float*)d_in[6];
    const float* ow  = (const float*)d_in[7];
    const float* ob  = (const float*)d_in[8];
    const float* w1  = (const float*)d_in[9];
    const float* b1  = (const float*)d_in[10];
    const float* w2  = (const float*)d_in[11];
    const float* b2  = (const float*)d_in[12];
    const float* g1  = (const float*)d_in[13];
    const float* be1 = (const float*)d_in[14];
    const float* g2  = (const float*)d_in[15];
    const float* be2 = (const float*)d_in[16];

    const size_t A    = (size_t)MR * DM;         // 3,145,728
    const size_t WD1  = (size_t)DM * DM;         // 589,824  (per layer)
    const size_t WQKV = (size_t)3 * DM * DM;     // 1,769,472 (per layer)
    const size_t WF1  = (size_t)DFF * DM;        // 2,359,296 (per layer)
    const size_t WF   = (size_t)NL * WF1;        // 4,718,592

    float*  bcat = (float*)d_ws;                 // NL * 2304 fp32
    ushort* p    = (ushort*)(bcat + (size_t)NL * QKVS);
    ushort* qkvwB = p; p += (size_t)NL * WQKV;
    ushort* owB   = p; p += (size_t)NL * WD1;
    ushort* w1B   = p; p += WF;
    ushort* w2B   = p; p += WF;
    ushort* xb    = p; p += A;
    ushort* qkvB  = p; p += 3 * A;
    ushort* oB    = p; p += A;
    ushort* yB    = p; p += A;
    ushort* h1    = p; p += A;
    ushort* ffh   = p;                            // MR*DFF = 12.58M elems

    // FF2 fp32 partials: dead-at-FF2 region qkvB..yB (10A B >= 8A B needed).
    float* partF = (float*)qkvB;
    // O-proj fp32 partials: dead-at-O region ffh (8A B, exact fit); consumed
    // by add_ln_sk BEFORE FF1 overwrites ffh.
    float* partO = (float*)ffh;

    // bias concat (device-to-device, async on stream — graph-capture safe)
    for (int l = 0; l < NL; ++l) {
        hipMemcpyAsync(bcat + (size_t)l * QKVS + 0,    qb + (size_t)l * DM,
                       DM * sizeof(float), hipMemcpyDeviceToDevice, stream);
        hipMemcpyAsync(bcat + (size_t)l * QKVS + DM,   kb + (size_t)l * DM,
                       DM * sizeof(float), hipMemcpyDeviceToDevice, stream);
        hipMemcpyAsync(bcat + (size_t)l * QKVS + 2*DM, vb + (size_t)l * DM,
                       DM * sizeof(float), hipMemcpyDeviceToDevice, stream);
    }

    // weight + src conversion (all sizes divisible by 1024)
    for (int l = 0; l < NL; ++l) {
        cvt<<<(int)(WD1 / 1024), 256, 0, stream>>>(
            qw + (size_t)l * WD1, qkvwB + (size_t)l * WQKV + 0,     (int)WD1);
        cvt<<<(int)(WD1 / 1024), 256, 0, stream>>>(
            kw + (size_t)l * WD1, qkvwB + (size_t)l * WQKV + WD1,   (int)WD1);
        cvt<<<(int)(WD1 / 1024), 256, 0, stream>>>(
            vw + (size_t)l * WD1, qkvwB + (size_t)l * WQKV + 2*WD1, (int)WD1);
    }
    cvt<<<(int)(NL * WD1 / 1024), 256, 0, stream>>>(ow, owB, (int)(NL * WD1));
    cvt<<<(int)(WF / 1024), 256, 0, stream>>>(w1, w1B, (int)WF);
    cvt<<<(int)(WF / 1024), 256, 0, stream>>>(w2, w2B, (int)WF);
    cvt<<<(int)(A  / 1024), 256, 0, stream>>>(src, xb, (int)A);

    const dim3 gQKV(QKVS / 128, MR / 128);      // (18, 32)  576 blocks
    const dim3 gOp(DM / 128, MR / 64, 2);       // (6, 64, 2) 768 blocks
    const dim3 gF1(DFF / 128, MR / 128);        // (24, 32)  768 blocks
    const dim3 gF2(DM / 128, MR / 64, 2);       // (6, 64, 2) 768 blocks
    const dim3 gA(SEQ / QT, NHD, BATCH);        // (32, 12, 2) 768 blocks

    for (int l = 0; l < NL; ++l) {
        const size_t bD = (size_t)l * DM;
        const size_t bF = (size_t)l * DFF;

        gemm128<<<gQKV, 256, 0, stream>>>(xb, qkvwB + (size_t)l * WQKV,
                                          bcat + (size_t)l * QKVS, qkvB,
                                          MR, QKVS, DM, 0);
        attn<<<gA, 256, 0, stream>>>(qkvB, qkvB + DM, qkvB + 2 * DM, oB);
        // O-proj split-K: K=768 -> 2 chunks of 384; fp32 partials in ffh
        gemm64<<<gOp, 256, 0, stream>>>(oB, owB + (size_t)l * WD1, nullptr,
                                        nullptr, partO, MR, DM, DM / 2, DM, 0);
        add_ln_sk<<<MR / 4, 256, 0, stream>>>(xb, partO, ob + bD,
                                              g1 + bD, be1 + bD,
                                              h1, nullptr, 0);
        gemm128<<<gF1, 256, 0, stream>>>(h1, w1B + (size_t)l * WF1, b1 + bF, ffh,
                                         MR, DFF, DM, 1);
        // FF2 split-K: K=3072 -> 2 chunks of 1536; fp32 partials in qkvB
        gemm64<<<gF2, 256, 0, stream>>>(ffh, w2B + (size_t)l * WF1, nullptr,
                                        nullptr, partF, MR, DM, DFF / 2, DFF, 0);
        if (l == NL - 1)
            add_ln_sk<<<MR / 4, 256, 0, stream>>>(h1, partF, b2 + bD,
                                                  g2 + bD, be2 + bD,
                                                  nullptr, (float*)d_out, 1);
        else
            add_ln_sk<<<MR / 4, 256, 0, stream>>>(h1, partF, b2 + bD,
                                                  g2 + bD, be2 + bD,
                                                  xb, nullptr, 0);
    }
}

// Round 10
// 455.458 us; speedup vs baseline: 1.0544x; 1.0105x over previous
//
#include <hip/hip_runtime.h>
#include <math.h>

// Problem constants
#define BATCH 2
#define SEQ   2048
#define DM    768
#define NHD   12
#define NL    2
#define DFF   3072
#define DH    64
#define HW    256            // WIN // 2
#define MR    (BATCH*SEQ)    // 4096
#define EPSF  1e-5f
#define SCALE 0.125f         // DH^-0.5
#define QKVS  2304           // fused qkv activation row stride

typedef __attribute__((ext_vector_type(8))) __bf16 bf16x8;
typedef __attribute__((ext_vector_type(4))) float  f32x4;

__device__ __forceinline__ ushort f2bu(float f) {
    union { __bf16 h; ushort u; } c;
    c.h = (__bf16)f;
    return c.u;
}
__device__ __forceinline__ float bu2f(ushort u) {
    union { uint u; float f; } c;
    c.u = ((uint)u) << 16;
    return c.f;
}

// async global->LDS, 16B per lane. LDS dest must be linear: uniform base +
// lane*16 within each wave (learn_hip m104).
__device__ __forceinline__ void gload16(const ushort* g, ushort* l) {
    __builtin_amdgcn_global_load_lds(
        (const __attribute__((address_space(1))) void*)g,
        (__attribute__((address_space(3))) void*)l, 16, 0, 0);
}

// XCD-aware chunked block remap (T1). Requires nwg % 8 == 0 (grids:
// 576/768). Pure permutation.
__device__ __forceinline__ void xcd_swz(int& bx, int& by, int& bz) {
    const int gx = gridDim.x, gy = gridDim.y;
    const int nwg = gx * gy * gridDim.z;
    int lin = bx + gx * (by + gy * bz);
    lin = (lin & 7) * (nwg >> 3) + (lin >> 3);
    bx = lin % gx;
    int rest = lin / gx;
    by = rest % gy;
    bz = rest / gy;
}

// ---------------------------------------------------------------------------
// fp32 -> bf16 cast, 4 elems/thread (n divisible by 1024)
// ---------------------------------------------------------------------------
__global__ __launch_bounds__(256) void cvt(const float* __restrict__ in,
                                           ushort* __restrict__ out, int n)
{
    int i = (blockIdx.x * 256 + threadIdx.x) * 4;
    if (i >= n) return;
    float4 v = *(const float4*)(in + i);
    ushort4 o;
    o.x = f2bu(v.x); o.y = f2bu(v.y); o.z = f2bu(v.z); o.w = f2bu(v.w);
    *(ushort4*)(out + i) = o;
}

// ---------------------------------------------------------------------------
// MFMA GEMM, 128x128 tile, BK=32, 4 waves (2x2), wave = 64x64 via 4x4
// fragments (0.5 ds_read_b128 per MFMA -- LDS-BW-optimal of our shapes).
// Counted-vmcnt 3-deep pipeline (T3+T4) + T2 XOR swizzle (linear gload_lds
// dest + inverse-swizzled global source + swizzled ds_read).
// Optional split-K: z = K-chunk; if gridDim.z > 1, write fp32 partials to
// part[z*M*N + ...]; else bf16 + bias (+relu). Kc = chunk len, ldk = row
// stride of A and W (= full K).
// Fragment layouts (learn_hip m89/m91, HW-verified):
//   A-frag: A[m = lane&15][k = (lane>>4)*8 + j]
//   B-frag: W[n = lane&15][k = (lane>>4)*8 + j]
//   C/D:    col(n) = lane&15, row(m) = (lane>>4)*4 + reg
// ---------------------------------------------------------------------------
#define STAGE128(bi, kt) do {                                           \
        const int _k0 = (kt) * 32;                                      \
        gload16(ag + _k0,                    &As[bi][t * 8]);           \
        gload16(ag + (size_t)64 * ldk + _k0, &As[bi][2048 + t * 8]);    \
        gload16(wg + _k0,                    &Ws[bi][t * 8]);           \
        gload16(wg + (size_t)64 * ldk + _k0, &Ws[bi][2048 + t * 8]);    \
    } while (0)

__global__ __launch_bounds__(256) void gemm128(
    const ushort* __restrict__ A, const ushort* __restrict__ W,
    const float* __restrict__ bias, ushort* __restrict__ C,
    float* __restrict__ part, int M, int N, int Kc, int ldk, int relu)
{
    __shared__ ushort As[3][128 * 32];
    __shared__ ushort Ws[3][128 * 32];

    int bxi = blockIdx.x, byi = blockIdx.y, bzi = blockIdx.z;
    xcd_swz(bxi, byi, bzi);

    const int t  = threadIdx.x;
    const int bm = byi * 128;
    const int bn = bxi * 128;
    const int z  = bzi;
    const int kbase = z * Kc;

    const int w    = t >> 6;
    const int lane = t & 63;
    const int quad = lane >> 4;
    const int lrow = lane & 15;
    const int wm   = (w >> 1) * 64;
    const int wn   = (w & 1) * 64;
    const int rx   = (lrow >> 1) & 3;          // read-side XOR (T2)
    const int rq   = (quad ^ rx) * 8;          // swizzled slot offset

    const int srow = t >> 2;                   // 0..63 (e=0), +64 for e=1
    const int scol = (((t & 3) ^ ((t >> 3) & 3)) * 8);
    const ushort* ag = A + (size_t)(bm + srow) * ldk + kbase + scol;
    const ushort* wg = W + (size_t)(bn + srow) * ldk + kbase + scol;

    f32x4 acc[4][4] = {};
    const int NT = Kc / 32;

    STAGE128(0, 0);
    STAGE128(1, 1);

    for (int kt = 0; kt < NT; ++kt) {
        if (kt + 1 < NT)
            asm volatile("s_waitcnt vmcnt(4)" ::: "memory");
        else
            asm volatile("s_waitcnt vmcnt(0)" ::: "memory");
        __builtin_amdgcn_s_barrier();

        const int cb = kt % 3;
        bf16x8 af[4], bfr[4];
#pragma unroll
        for (int i = 0; i < 4; ++i)
            af[i] = *(const bf16x8*)&As[cb][(wm + i * 16 + lrow) * 32 + rq];
#pragma unroll
        for (int j = 0; j < 4; ++j)
            bfr[j] = *(const bf16x8*)&Ws[cb][(wn + j * 16 + lrow) * 32 + rq];

#pragma unroll
        for (int i = 0; i < 4; ++i)
#pragma unroll
            for (int j = 0; j < 4; ++j)
                acc[i][j] = __builtin_amdgcn_mfma_f32_16x16x32_bf16(
                    af[i], bfr[j], acc[i][j], 0, 0, 0);

        if (kt + 2 < NT) {
            const int sb = (kt + 2) % 3;
            STAGE128(sb, kt + 2);
        }
    }

    if (gridDim.z > 1) {
        float* po = part + (size_t)z * M * N;
#pragma unroll
        for (int j = 0; j < 4; ++j) {
            const int col = bn + wn + j * 16 + lrow;
#pragma unroll
            for (int i = 0; i < 4; ++i) {
                const int rb = bm + wm + i * 16 + quad * 4;
#pragma unroll
                for (int r = 0; r < 4; ++r)
                    po[(size_t)(rb + r) * N + col] = acc[i][j][r];
            }
        }
    } else {
#pragma unroll
        for (int j = 0; j < 4; ++j) {
            const int col = bn + wn + j * 16 + lrow;
            const float bv = bias[col];
#pragma unroll
            for (int i = 0; i < 4; ++i) {
                const int rb = bm + wm + i * 16 + quad * 4;
#pragma unroll
                for (int r = 0; r < 4; ++r) {
                    float vv = acc[i][j][r] + bv;
                    if (relu) vv = fmaxf(vv, 0.f);
                    C[(size_t)(rb + r) * N + col] = f2bu(vv);
                }
            }
        }
    }
}

// ---------------------------------------------------------------------------
// MFMA GEMM, BM=64 x BN=128, BK=32, 4 waves (2x2), wave = 32x64 via 2x4
// fragments. Counted-vmcnt 3-deep pipeline + T2 XOR swizzle. Optional
// split-K as above. (Used only for the short-K O-projection.)
// ---------------------------------------------------------------------------
#define STAGE64(bi, kt) do {                                            \
        const int _k0 = (kt) * 32;                                      \
        gload16(ag + _k0,                    &As[bi][t * 8]);           \
        gload16(wg + _k0,                    &Ws[bi][t * 8]);           \
        gload16(wg + (size_t)64 * ldk + _k0, &Ws[bi][2048 + t * 8]);    \
    } while (0)

__global__ __launch_bounds__(256) void gemm64(
    const ushort* __restrict__ A, const ushort* __restrict__ W,
    const float* __restrict__ bias, ushort* __restrict__ C,
    float* __restrict__ part, int M, int N, int Kc, int ldk, int relu)
{
    __shared__ ushort As[3][64 * 32];
    __shared__ ushort Ws[3][128 * 32];

    int bxi = blockIdx.x, byi = blockIdx.y, bzi = blockIdx.z;
    xcd_swz(bxi, byi, bzi);

    const int t  = threadIdx.x;
    const int bm = byi * 64;
    const int bn = bxi * 128;
    const int z  = bzi;
    const int kbase = z * Kc;

    const int w    = t >> 6;
    const int lane = t & 63;
    const int quad = lane >> 4;
    const int lrow = lane & 15;
    const int wm   = (w >> 1) * 32;
    const int wn   = (w & 1) * 64;
    const int rx   = (lrow >> 1) & 3;
    const int rq   = (quad ^ rx) * 8;

    const int srow = t >> 2;          // 0..63
    const int scol = (((t & 3) ^ ((t >> 3) & 3)) * 8);
    const ushort* ag = A + (size_t)(bm + srow) * ldk + kbase + scol;
    const ushort* wg = W + (size_t)(bn + srow) * ldk + kbase + scol;

    f32x4 acc[2][4] = {};
    const int NT = Kc / 32;

    STAGE64(0, 0);
    STAGE64(1, 1);

    for (int kt = 0; kt < NT; ++kt) {
        if (kt + 1 < NT)
            asm volatile("s_waitcnt vmcnt(3)" ::: "memory");
        else
            asm volatile("s_waitcnt vmcnt(0)" ::: "memory");
        __builtin_amdgcn_s_barrier();

        const int cb = kt % 3;
        bf16x8 af[2], bfr[4];
#pragma unroll
        for (int i = 0; i < 2; ++i)
            af[i] = *(const bf16x8*)&As[cb][(wm + i * 16 + lrow) * 32 + rq];
#pragma unroll
        for (int j = 0; j < 4; ++j)
            bfr[j] = *(const bf16x8*)&Ws[cb][(wn + j * 16 + lrow) * 32 + rq];

#pragma unroll
        for (int i = 0; i < 2; ++i)
#pragma unroll
            for (int j = 0; j < 4; ++j)
                acc[i][j] = __builtin_amdgcn_mfma_f32_16x16x32_bf16(
                    af[i], bfr[j], acc[i][j], 0, 0, 0);

        if (kt + 2 < NT) {
            const int sb = (kt + 2) % 3;
            STAGE64(sb, kt + 2);
        }
    }

    if (gridDim.z > 1) {
        float* po = part + (size_t)z * M * N;
#pragma unroll
        for (int j = 0; j < 4; ++j) {
            const int col = bn + wn + j * 16 + lrow;
#pragma unroll
            for (int i = 0; i < 2; ++i) {
                const int rb = bm + wm + i * 16 + quad * 4;
#pragma unroll
                for (int r = 0; r < 4; ++r)
                    po[(size_t)(rb + r) * N + col] = acc[i][j][r];
            }
        }
    } else {
#pragma unroll
        for (int j = 0; j < 4; ++j) {
            const int col = bn + wn + j * 16 + lrow;
            const float bv = bias[col];
#pragma unroll
            for (int i = 0; i < 2; ++i) {
                const int rb = bm + wm + i * 16 + quad * 4;
#pragma unroll
                for (int r = 0; r < 4; ++r) {
                    float vv = acc[i][j][r] + bv;
                    if (relu) vv = fmaxf(vv, 0.f);
                    C[(size_t)(rb + r) * N + col] = f2bu(vv);
                }
            }
        }
    }
}

// ---------------------------------------------------------------------------
// Banded attention, flash single pass, double-buffered, swapped QK^T,
// reg-local online softmax, defer-max, mask hoisting. (Unchanged from R8.)
// ---------------------------------------------------------------------------
#define QT  64
#define NCH 9    // union window 64+512 = 576 keys
#define KP  72   // LDS pitch in bf16 (144 B rows: 16B-aligned, 2-way max)

__global__ __launch_bounds__(256) void attn(
    const ushort* __restrict__ q, const ushort* __restrict__ k,
    const ushort* __restrict__ v, ushort* __restrict__ o)
{
    __shared__ ushort kv[2][64][KP];   // K chunk [key][dh]
    __shared__ ushort vt[2][64][KP];   // V^T chunk [dh][key], XOR-swizzled
    __shared__ ushort sc[QT][KP];      // Q staging, then per-chunk P tiles

    int bxi = blockIdx.x, byi = blockIdx.y, bzi = blockIdx.z;
    xcd_swz(bxi, byi, bzi);            // seq-neighbors share KV -> same XCD

    const int t    = threadIdx.x;
    const int i0   = bxi * QT;
    const int h    = byi;
    const int b    = bzi;
    const size_t ibase = (size_t)b * SEQ * QKVS + (size_t)h * DH;  // q/k/v
    const size_t obase = (size_t)b * SEQ * DM   + (size_t)h * DH;  // o

    const int w    = t >> 6;
    const int lane = t & 63;
    const int quad = lane >> 4;
    const int lrow = lane & 15;
    const int qrow = w * 16;            // wave's 16 query rows

    const int jstart = i0 - HW;

    const int sjj[2] = { t >> 3, (t + 256) >> 3 };
    const int sd0 = (t & 7) * 8;

    // ---- stage Q into sc + load chunk 0 into regs -------------------------
#pragma unroll
    for (int e = 0; e < 2; ++e) {
        int idx = t + 256 * e;
        int qi = idx >> 3, d0 = (idx & 7) * 8;
        uint4 raw = *(const uint4*)(q + ibase + (size_t)(i0 + qi) * QKVS + d0);
        *(uint4*)&sc[qi][d0] = raw;
    }
    uint4 kr[2], vr[2];
#pragma unroll
    for (int e = 0; e < 2; ++e) {
        int j = jstart + sjj[e];
        kr[e] = make_uint4(0, 0, 0, 0);
        vr[e] = make_uint4(0, 0, 0, 0);
        if (j >= 0 && j < SEQ) {
            kr[e] = *(const uint4*)(k + ibase + (size_t)j * QKVS + sd0);
            vr[e] = *(const uint4*)(v + ibase + (size_t)j * QKVS + sd0);
        }
    }
#pragma unroll
    for (int e = 0; e < 2; ++e) {
        *(uint4*)&kv[0][sjj[e]][sd0] = kr[e];
        const ushort* u = (const ushort*)&vr[e];
#pragma unroll
        for (int x = 0; x < 8; ++x) {
            int dh  = sd0 + x;
            int blk = ((sjj[e] >> 3) ^ (dh >> 3)) & 7;
            vt[0][dh][blk * 8 + (sjj[e] & 7)] = u[x];
        }
    }
    __syncthreads();   // publish sc (Q) and buf0

    // Q fragments as the B-operand (chunk-invariant): B[n=lrow]=Q[qrow+lrow]
    const bf16x8 a0 = *(const bf16x8*)&sc[qrow + lrow][quad * 8];
    const bf16x8 a1 = *(const bf16x8*)&sc[qrow + lrow][32 + quad * 8];

    float m_s = -1e20f, l_s = 0.f;     // per-lane: running max/sum of q-row
    f32x4 oacc[4] = {};

    for (int c = 0; c < NCH; ++c) {
        const int cur = c & 1;
        const int j0  = jstart + c * 64;

        // ---- issue chunk c+1 global loads ---------------------------------
        if (c + 1 < NCH) {
            const int j0n = jstart + (c + 1) * 64;
#pragma unroll
            for (int e = 0; e < 2; ++e) {
                int j = j0n + sjj[e];
                kr[e] = make_uint4(0, 0, 0, 0);
                vr[e] = make_uint4(0, 0, 0, 0);
                if (j >= 0 && j < SEQ) {
                    kr[e] = *(const uint4*)(k + ibase + (size_t)j * QKVS + sd0);
                    vr[e] = *(const uint4*)(v + ibase + (size_t)j * QKVS + sd0);
                }
            }
        }

        // ---- QK^T swapped: D[m=key][n=q]; lane = 16 keys of q=qrow+lrow ---
        const bool full = (c >= 1) && (c <= 7) && (j0 >= 0) && (j0 + 64 <= SEQ);
        float p[4][4];   // [kt][r] = P[q][key = kt*16 + quad*4 + r]
#pragma unroll
        for (int kt = 0; kt < 4; ++kt) {
            const int krow = kt * 16;
            bf16x8 kf0 = *(const bf16x8*)&kv[cur][krow + lrow][quad * 8];
            bf16x8 kf1 = *(const bf16x8*)&kv[cur][krow + lrow][32 + quad * 8];
            f32x4 acc = {};
            acc = __builtin_amdgcn_mfma_f32_16x16x32_bf16(kf0, a0, acc, 0, 0, 0);
            acc = __builtin_amdgcn_mfma_f32_16x16x32_bf16(kf1, a1, acc, 0, 0, 0);
            if (full) {
#pragma unroll
                for (int r = 0; r < 4; ++r) p[kt][r] = acc[r] * SCALE;
            } else {
                const int ig = i0 + qrow + lrow;
#pragma unroll
                for (int r = 0; r < 4; ++r) {
                    const int jg = j0 + krow + quad * 4 + r;
                    bool ok = (jg >= 0) && (jg < SEQ) &&
                              (jg >= ig - HW) && (jg <= ig + HW);
                    p[kt][r] = ok ? acc[r] * SCALE : -1e30f;
                }
            }
        }

        // ---- online softmax: reg-local + cross-quad reduce ----------------
        float cm = p[0][0];
#pragma unroll
        for (int kt = 0; kt < 4; ++kt)
#pragma unroll
            for (int r = 0; r < 4; ++r) cm = fmaxf(cm, p[kt][r]);
        cm = fmaxf(cm, __shfl_xor(cm, 16));
        cm = fmaxf(cm, __shfl_xor(cm, 32));

        const bool resc = !__all(cm <= m_s + 8.f);   // defer-max THR=8
        float f = 1.f;
        if (resc) {
            const float mn = fmaxf(m_s, cm);
            f = __expf(m_s - mn);
            m_s = mn;
        }
        float cs = 0.f;
#pragma unroll
        for (int kt = 0; kt < 4; ++kt)
#pragma unroll
            for (int r = 0; r < 4; ++r) {
                float e = __expf(p[kt][r] - m_s);
                p[kt][r] = e;
                cs += e;
            }
        cs += __shfl_xor(cs, 16);
        cs += __shfl_xor(cs, 32);
        l_s = l_s * f + cs;
        if (resc) {
            float f4[4];
#pragma unroll
            for (int r = 0; r < 4; ++r) f4[r] = __shfl(f, quad * 4 + r);
#pragma unroll
            for (int nt = 0; nt < 4; ++nt)
#pragma unroll
                for (int r = 0; r < 4; ++r) oacc[nt][r] *= f4[r];
        }

        // ---- P to sc: 4x ushort4 at sc[q][kt*16 + quad*4] -----------------
#pragma unroll
        for (int kt = 0; kt < 4; ++kt) {
            ushort4 pw;
            pw.x = f2bu(p[kt][0]);
            pw.y = f2bu(p[kt][1]);
            pw.z = f2bu(p[kt][2]);
            pw.w = f2bu(p[kt][3]);
            *(ushort4*)&sc[qrow + lrow][kt * 16 + quad * 4] = pw;
        }

        // ---- PV: O[q][dh] += P . V^T (A-frag read unchanged) --------------
        bf16x8 pa0 = *(const bf16x8*)&sc[qrow + lrow][quad * 8];
        bf16x8 pa1 = *(const bf16x8*)&sc[qrow + lrow][32 + quad * 8];
#pragma unroll
        for (int nt = 0; nt < 4; ++nt) {
            const int dh  = nt * 16 + lrow;
            const int rsw = (dh >> 3) & 7;
            bf16x8 b0 = *(const bf16x8*)&vt[cur][dh][((quad)     ^ rsw) * 8];
            bf16x8 b1 = *(const bf16x8*)&vt[cur][dh][((quad + 4) ^ rsw) * 8];
            oacc[nt] = __builtin_amdgcn_mfma_f32_16x16x32_bf16(pa0, b0, oacc[nt], 0, 0, 0);
            oacc[nt] = __builtin_amdgcn_mfma_f32_16x16x32_bf16(pa1, b1, oacc[nt], 0, 0, 0);
        }

        // ---- write chunk c+1 regs to buf[cur^1] ---------------------------
        if (c + 1 < NCH) {
            const int nxt = cur ^ 1;
#pragma unroll
            for (int e = 0; e < 2; ++e) {
                *(uint4*)&kv[nxt][sjj[e]][sd0] = kr[e];
                const ushort* u = (const ushort*)&vr[e];
#pragma unroll
                for (int x = 0; x < 8; ++x) {
                    int dh  = sd0 + x;
                    int blk = ((sjj[e] >> 3) ^ (dh >> 3)) & 7;
                    vt[nxt][dh][blk * 8 + (sjj[e] & 7)] = u[x];
                }
            }
        }
        __syncthreads();   // single barrier: publishes buf[nxt], drains buf[cur]
    }

    // ---- write O: col(dh) = nt*16 + lrow, row(q) = qrow + quad*4 + r ------
    const float inv = 1.f / l_s;          // lane's q-row = qrow + lrow
    float inv4[4];
#pragma unroll
    for (int r = 0; r < 4; ++r) inv4[r] = __shfl(inv, quad * 4 + r);
#pragma unroll
    for (int r = 0; r < 4; ++r) {
        const int qi = i0 + qrow + quad * 4 + r;
#pragma unroll
        for (int nt = 0; nt < 4; ++nt)
            o[obase + (size_t)qi * DM + nt * 16 + lrow] = f2bu(oacc[nt][r] * inv4[r]);
    }
}

// ---------------------------------------------------------------------------
// Fused split-K reduce (2 planes) + residual + LayerNorm (O-proj tail).
// ---------------------------------------------------------------------------
__global__ __launch_bounds__(256) void add_ln_sk(
    const ushort* __restrict__ xa, const float* __restrict__ pp,
    const float* __restrict__ bias, const float* __restrict__ g,
    const float* __restrict__ be,
    ushort* __restrict__ ob, float* __restrict__ of, int fin)
{
    const int r = blockIdx.x * 4 + (threadIdx.x >> 6);
    const int t = threadIdx.x & 63;
    const size_t off = (size_t)r * DM;
    const size_t pl  = (size_t)MR * DM;
    float sv[12];
    float s1 = 0.f, s2 = 0.f;
#pragma unroll
    for (int ii = 0; ii < 12; ++ii) {
        const int c = t + 64 * ii;
        float vv = bu2f(xa[off + c]) + pp[off + c] + pp[pl + off + c] + bias[c];
        sv[ii] = vv; s1 += vv; s2 += vv * vv;
    }
#pragma unroll
    for (int o2 = 32; o2; o2 >>= 1) {
        s1 += __shfl_xor(s1, o2);
        s2 += __shfl_xor(s2, o2);
    }
    const float mean = s1 * (1.f / 768.f);
    const float rstd = rsqrtf(s2 * (1.f / 768.f) - mean * mean + EPSF);
#pragma unroll
    for (int ii = 0; ii < 12; ++ii) {
        const int c = t + 64 * ii;
        float v = (sv[ii] - mean) * rstd * g[c] + be[c];
        if (fin) of[off + c] = v;
        else     ob[off + c] = f2bu(v);
    }
}

// ---------------------------------------------------------------------------
// Fused split-K reduce (3 planes) + residual + LayerNorm (FF2 tail).
// ---------------------------------------------------------------------------
__global__ __launch_bounds__(256) void add_ln_sk3(
    const ushort* __restrict__ xa, const float* __restrict__ pp,
    const float* __restrict__ bias, const float* __restrict__ g,
    const float* __restrict__ be,
    ushort* __restrict__ ob, float* __restrict__ of, int fin)
{
    const int r = blockIdx.x * 4 + (threadIdx.x >> 6);
    const int t = threadIdx.x & 63;
    const size_t off = (size_t)r * DM;
    const size_t pl  = (size_t)MR * DM;
    float sv[12];
    float s1 = 0.f, s2 = 0.f;
#pragma unroll
    for (int ii = 0; ii < 12; ++ii) {
        const int c = t + 64 * ii;
        float vv = bu2f(xa[off + c]) + pp[off + c] + pp[pl + off + c]
                 + pp[2 * pl + off + c] + bias[c];
        sv[ii] = vv; s1 += vv; s2 += vv * vv;
    }
#pragma unroll
    for (int o2 = 32; o2; o2 >>= 1) {
        s1 += __shfl_xor(s1, o2);
        s2 += __shfl_xor(s2, o2);
    }
    const float mean = s1 * (1.f / 768.f);
    const float rstd = rsqrtf(s2 * (1.f / 768.f) - mean * mean + EPSF);
#pragma unroll
    for (int ii = 0; ii < 12; ++ii) {
        const int c = t + 64 * ii;
        float v = (sv[ii] - mean) * rstd * g[c] + be[c];
        if (fin) of[off + c] = v;
        else     ob[off + c] = f2bu(v);
    }
}

// ---------------------------------------------------------------------------
// Host orchestration.
// Buffer lifetime plan (x alternates xb -> x2 so partial regions are dead):
//   partF (FF2, 3 fp32 planes = 6A ushorts) = contiguous [xb..yB]  (all dead
//     at FF2: residual lives in h1; x_next goes to x2/d_out, outside region)
//   partO (O-proj, 2 fp32 planes = 4A ushorts) = ffh  (dead at O-proj both
//     layers; overwritten later by FF1 after the tail consumed it)
// ---------------------------------------------------------------------------
extern "C" void kernel_launch(void* const* d_in, const int* in_sizes, int n_in,
                              void* d_out, int out_size, void* d_ws, size_t ws_size,
                              hipStream_t stream) {
    (void)in_sizes; (void)n_in; (void)out_size; (void)ws_size;
    const float* src = (const float*)d_in[0];
    const float* qw  = (const float*)d_in[1];
    const float* qb  = (const float*)d_in[2];
    const float* kw  = (const float*)d_in[3];
    const float* kb  = (const float*)d_in[4];
    const float* vw  = (const float*)d_in[5];
    const float* vb  = (const float*)d_in[6];
    const float* ow  = (const float*)d_in[7];
    const float* ob  = (const float*)d_in[8];
    const float* w1  = (const float*)d_in[9];
    const float* b1  = (const float*)d_in[10];
    const float* w2  = (const float*)d_in[11];
    const float* b2  = (const float*)d_in[12];
    const float* g1  = (const float*)d_in[13];
    const float* be1 = (const float*)d_in[14];
    const float* g2  = (const float*)d_in[15];
    const float* be2 = (const float*)d_in[16];

    const size_t A    = (size_t)MR * DM;         // 3,145,728
    const size_t WD1  = (size_t)DM * DM;         // 589,824  (per layer)
    const size_t WQKV = (size_t)3 * DM * DM;     // 1,769,472 (per layer)
    const size_t WF1  = (size_t)DFF * DM;        // 2,359,296 (per layer)
    const size_t WF   = (size_t)NL * WF1;        // 4,718,592

    float*  bcat = (float*)d_ws;                 // NL * 2304 fp32
    ushort* p    = (ushort*)(bcat + (size_t)NL * QKVS);
    ushort* qkvwB = p; p += (size_t)NL * WQKV;
    ushort* owB   = p; p += (size_t)NL * WD1;
    ushort* w1B   = p; p += WF;
    ushort* w2B   = p; p += WF;
    ushort* xb    = p; p += A;       // x (layer 0) / FF2 partial plane 0
    ushort* qkvB  = p; p += 3 * A;   // qkv          / FF2 partials
    ushort* oB    = p; p += A;       // attn out     / FF2 partials
    ushort* yB    = p; p += A;       // (dead)       / FF2 partials
    ushort* h1    = p; p += A;       // post-LN1 residual
    ushort* ffh   = p; p += 4 * A;   // FF1 out (4A = MR*DFF) / O-proj partials
    ushort* x2    = p;               // x (layer 1)

    float* partF = (float*)xb;       // 3 planes: [xb..yB] = 6A ushorts
    float* partO = (float*)ffh;      // 2 planes: 4A ushorts

    // bias concat (device-to-device, async on stream — graph-capture safe)
    for (int l = 0; l < NL; ++l) {
        hipMemcpyAsync(bcat + (size_t)l * QKVS + 0,    qb + (size_t)l * DM,
                       DM * sizeof(float), hipMemcpyDeviceToDevice, stream);
        hipMemcpyAsync(bcat + (size_t)l * QKVS + DM,   kb + (size_t)l * DM,
                       DM * sizeof(float), hipMemcpyDeviceToDevice, stream);
        hipMemcpyAsync(bcat + (size_t)l * QKVS + 2*DM, vb + (size_t)l * DM,
                       DM * sizeof(float), hipMemcpyDeviceToDevice, stream);
    }

    // weight + src conversion (all sizes divisible by 1024)
    for (int l = 0; l < NL; ++l) {
        cvt<<<(int)(WD1 / 1024), 256, 0, stream>>>(
            qw + (size_t)l * WD1, qkvwB + (size_t)l * WQKV + 0,     (int)WD1);
        cvt<<<(int)(WD1 / 1024), 256, 0, stream>>>(
            kw + (size_t)l * WD1, qkvwB + (size_t)l * WQKV + WD1,   (int)WD1);
        cvt<<<(int)(WD1 / 1024), 256, 0, stream>>>(
            vw + (size_t)l * WD1, qkvwB + (size_t)l * WQKV + 2*WD1, (int)WD1);
    }
    cvt<<<(int)(NL * WD1 / 1024), 256, 0, stream>>>(ow, owB, (int)(NL * WD1));
    cvt<<<(int)(WF / 1024), 256, 0, stream>>>(w1, w1B, (int)WF);
    cvt<<<(int)(WF / 1024), 256, 0, stream>>>(w2, w2B, (int)WF);
    cvt<<<(int)(A  / 1024), 256, 0, stream>>>(src, xb, (int)A);

    const dim3 gQKV(QKVS / 128, MR / 128);      // (18, 32)  576 blocks
    const dim3 gOp(DM / 128, MR / 64, 2);       // (6, 64, 2) 768 blocks
    const dim3 gF1(DFF / 128, MR / 128);        // (24, 32)  768 blocks
    const dim3 gF2(DM / 128, MR / 128, 3);      // (6, 32, 3) 576 blocks
    const dim3 gA(SEQ / QT, NHD, BATCH);        // (32, 12, 2) 768 blocks

    for (int l = 0; l < NL; ++l) {
        const size_t bD = (size_t)l * DM;
        const size_t bF = (size_t)l * DFF;
        const ushort* xin = (l == 0) ? xb : x2;

        gemm128<<<gQKV, 256, 0, stream>>>(xin, qkvwB + (size_t)l * WQKV,
                                          bcat + (size_t)l * QKVS, qkvB,
                                          nullptr, MR, QKVS, DM, DM, 0);
        attn<<<gA, 256, 0, stream>>>(qkvB, qkvB + DM, qkvB + 2 * DM, oB);
        // O-proj split-K: K=768 -> 2 chunks of 384; fp32 partials in ffh
        gemm64<<<gOp, 256, 0, stream>>>(oB, owB + (size_t)l * WD1, nullptr,
                                        nullptr, partO, MR, DM, DM / 2, DM, 0);
        add_ln_sk<<<MR / 4, 256, 0, stream>>>(xin, partO, ob + bD,
                                              g1 + bD, be1 + bD,
                                              h1, nullptr, 0);
        gemm128<<<gF1, 256, 0, stream>>>(h1, w1B + (size_t)l * WF1, b1 + bF, ffh,
                                         nullptr, MR, DFF, DM, DM, 1);
        // FF2 split-K: K=3072 -> 3 chunks of 1024 (128^2 tile: 0.5 LDS-reads
        // per MFMA vs gemm64's 0.75); fp32 partials in [xb..yB]
        gemm128<<<gF2, 256, 0, stream>>>(ffh, w2B + (size_t)l * WF1, nullptr,
                                         nullptr, partF, MR, DM, DFF / 3, DFF, 0);
        if (l == NL - 1)
            add_ln_sk3<<<MR / 4, 256, 0, stream>>>(h1, partF, b2 + bD,
                                                   g2 + bD, be2 + bD,
                                                   nullptr, (float*)d_out, 1);
        else
            add_ln_sk3<<<MR / 4, 256, 0, stream>>>(h1, partF, b2 + bD,
                                                   g2 + bD, be2 + bD,
                                                   x2, nullptr, 0);
    }
}

// Round 11
// 431.408 us; speedup vs baseline: 1.1131x; 1.0557x over previous
//
#include <hip/hip_runtime.h>
#include <math.h>

// Problem constants
#define BATCH 2
#define SEQ   2048
#define DM    768
#define NHD   12
#define NL    2
#define DFF   3072
#define DH    64
#define HW    256            // WIN // 2
#define MR    (BATCH*SEQ)    // 4096
#define EPSF  1e-5f
#define SCALE 0.125f         // DH^-0.5
#define QKVS  2304           // fused qkv activation row stride

typedef __attribute__((ext_vector_type(8))) __bf16 bf16x8;
typedef __attribute__((ext_vector_type(4))) float  f32x4;

__device__ __forceinline__ ushort f2bu(float f) {
    union { __bf16 h; ushort u; } c;
    c.h = (__bf16)f;
    return c.u;
}
__device__ __forceinline__ float bu2f(ushort u) {
    union { uint u; float f; } c;
    c.u = ((uint)u) << 16;
    return c.f;
}

// async global->LDS, 16B per lane. LDS dest must be linear: uniform base +
// lane*16 within each wave (learn_hip m104).
__device__ __forceinline__ void gload16(const ushort* g, ushort* l) {
    __builtin_amdgcn_global_load_lds(
        (const __attribute__((address_space(1))) void*)g,
        (__attribute__((address_space(3))) void*)l, 16, 0, 0);
}

// XCD-aware chunked block remap (T1). Requires nwg % 8 == 0 (grids:
// 576/768). Pure permutation.
__device__ __forceinline__ void xcd_swz(int& bx, int& by, int& bz) {
    const int gx = gridDim.x, gy = gridDim.y;
    const int nwg = gx * gy * gridDim.z;
    int lin = bx + gx * (by + gy * bz);
    lin = (lin & 7) * (nwg >> 3) + (lin >> 3);
    bx = lin % gx;
    int rest = lin / gx;
    by = rest % gy;
    bz = rest / gy;
}

// ---------------------------------------------------------------------------
// fp32 -> bf16 cast, 4 elems/thread (n divisible by 1024)
// ---------------------------------------------------------------------------
__global__ __launch_bounds__(256) void cvt(const float* __restrict__ in,
                                           ushort* __restrict__ out, int n)
{
    int i = (blockIdx.x * 256 + threadIdx.x) * 4;
    if (i >= n) return;
    float4 v = *(const float4*)(in + i);
    ushort4 o;
    o.x = f2bu(v.x); o.y = f2bu(v.y); o.z = f2bu(v.z); o.w = f2bu(v.w);
    *(ushort4*)(out + i) = o;
}

// ---------------------------------------------------------------------------
// 3-source fp32 -> bf16 interleaved cast (QKV weights): dst layer block =
// [q | k | v], each seg elems. grid = (3*seg/1024, NL). Replaces 6 launches.
// ---------------------------------------------------------------------------
__global__ __launch_bounds__(256) void cvt3(
    const float* __restrict__ s0, const float* __restrict__ s1,
    const float* __restrict__ s2, ushort* __restrict__ dst,
    int seg, int dstride)
{
    const int l = blockIdx.y;
    int i = (blockIdx.x * 256 + threadIdx.x) * 4;
    if (i >= 3 * seg) return;
    const float* s;
    int off;
    if (i < seg)           { s = s0 + (size_t)l * seg; off = i; }
    else if (i < 2 * seg)  { s = s1 + (size_t)l * seg; off = i - seg; }
    else                   { s = s2 + (size_t)l * seg; off = i - 2 * seg; }
    float4 v = *(const float4*)(s + off);
    ushort4 o;
    o.x = f2bu(v.x); o.y = f2bu(v.y); o.z = f2bu(v.z); o.w = f2bu(v.w);
    *(ushort4*)(dst + (size_t)l * dstride + i) = o;
}

// ---------------------------------------------------------------------------
// bias concat: bcat[l*QKVS + {0,DM,2DM}] = {qb,kb,vb}[l*DM]. Replaces 6
// hipMemcpyAsync nodes. grid = (NL*3), 256 thr, 3 elems/thread.
// ---------------------------------------------------------------------------
__global__ __launch_bounds__(256) void bias_cat(
    const float* __restrict__ qb, const float* __restrict__ kb,
    const float* __restrict__ vb, float* __restrict__ bcat)
{
    const int b = blockIdx.x;
    const int l = b / 3, wsel = b % 3;
    const float* s = (wsel == 0) ? qb : (wsel == 1) ? kb : vb;
    s += (size_t)l * DM;
    float* d = bcat + (size_t)l * QKVS + wsel * DM;
#pragma unroll
    for (int e = 0; e < 3; ++e) {
        int c = threadIdx.x + 256 * e;
        d[c] = s[c];
    }
}

// ---------------------------------------------------------------------------
// MFMA GEMM, 128x128 tile, BK=32, 4 waves (2x2), wave = 64x64 via 4x4
// fragments (0.5 ds_read_b128 per MFMA -- LDS-BW-optimal of our shapes).
// Counted-vmcnt 3-deep pipeline (T3+T4) + T2 XOR swizzle (linear gload_lds
// dest + inverse-swizzled global source + swizzled ds_read) + T5 setprio
// around the MFMA cluster.
// Optional split-K: z = K-chunk; if gridDim.z > 1, write fp32 partials to
// part[z*M*N + ...]; else bf16 + bias (+relu). Kc = chunk len, ldk = row
// stride of A and W (= full K).
// Fragment layouts (learn_hip m89/m91, HW-verified):
//   A-frag: A[m = lane&15][k = (lane>>4)*8 + j]
//   B-frag: W[n = lane&15][k = (lane>>4)*8 + j]
//   C/D:    col(n) = lane&15, row(m) = (lane>>4)*4 + reg
// ---------------------------------------------------------------------------
#define STAGE128(bi, kt) do {                                           \
        const int _k0 = (kt) * 32;                                      \
        gload16(ag + _k0,                    &As[bi][t * 8]);           \
        gload16(ag + (size_t)64 * ldk + _k0, &As[bi][2048 + t * 8]);    \
        gload16(wg + _k0,                    &Ws[bi][t * 8]);           \
        gload16(wg + (size_t)64 * ldk + _k0, &Ws[bi][2048 + t * 8]);    \
    } while (0)

__global__ __launch_bounds__(256) void gemm128(
    const ushort* __restrict__ A, const ushort* __restrict__ W,
    const float* __restrict__ bias, ushort* __restrict__ C,
    float* __restrict__ part, int M, int N, int Kc, int ldk, int relu)
{
    __shared__ ushort As[3][128 * 32];
    __shared__ ushort Ws[3][128 * 32];

    int bxi = blockIdx.x, byi = blockIdx.y, bzi = blockIdx.z;
    xcd_swz(bxi, byi, bzi);

    const int t  = threadIdx.x;
    const int bm = byi * 128;
    const int bn = bxi * 128;
    const int z  = bzi;
    const int kbase = z * Kc;

    const int w    = t >> 6;
    const int lane = t & 63;
    const int quad = lane >> 4;
    const int lrow = lane & 15;
    const int wm   = (w >> 1) * 64;
    const int wn   = (w & 1) * 64;
    const int rx   = (lrow >> 1) & 3;          // read-side XOR (T2)
    const int rq   = (quad ^ rx) * 8;          // swizzled slot offset

    const int srow = t >> 2;                   // 0..63 (e=0), +64 for e=1
    const int scol = (((t & 3) ^ ((t >> 3) & 3)) * 8);
    const ushort* ag = A + (size_t)(bm + srow) * ldk + kbase + scol;
    const ushort* wg = W + (size_t)(bn + srow) * ldk + kbase + scol;

    f32x4 acc[4][4] = {};
    const int NT = Kc / 32;

    STAGE128(0, 0);
    STAGE128(1, 1);

    for (int kt = 0; kt < NT; ++kt) {
        if (kt + 1 < NT)
            asm volatile("s_waitcnt vmcnt(4)" ::: "memory");
        else
            asm volatile("s_waitcnt vmcnt(0)" ::: "memory");
        __builtin_amdgcn_s_barrier();

        const int cb = kt % 3;
        bf16x8 af[4], bfr[4];
#pragma unroll
        for (int i = 0; i < 4; ++i)
            af[i] = *(const bf16x8*)&As[cb][(wm + i * 16 + lrow) * 32 + rq];
#pragma unroll
        for (int j = 0; j < 4; ++j)
            bfr[j] = *(const bf16x8*)&Ws[cb][(wn + j * 16 + lrow) * 32 + rq];

        __builtin_amdgcn_s_setprio(1);
#pragma unroll
        for (int i = 0; i < 4; ++i)
#pragma unroll
            for (int j = 0; j < 4; ++j)
                acc[i][j] = __builtin_amdgcn_mfma_f32_16x16x32_bf16(
                    af[i], bfr[j], acc[i][j], 0, 0, 0);
        __builtin_amdgcn_s_setprio(0);

        if (kt + 2 < NT) {
            const int sb = (kt + 2) % 3;
            STAGE128(sb, kt + 2);
        }
    }

    if (gridDim.z > 1) {
        float* po = part + (size_t)z * M * N;
#pragma unroll
        for (int j = 0; j < 4; ++j) {
            const int col = bn + wn + j * 16 + lrow;
#pragma unroll
            for (int i = 0; i < 4; ++i) {
                const int rb = bm + wm + i * 16 + quad * 4;
#pragma unroll
                for (int r = 0; r < 4; ++r)
                    po[(size_t)(rb + r) * N + col] = acc[i][j][r];
            }
        }
    } else {
#pragma unroll
        for (int j = 0; j < 4; ++j) {
            const int col = bn + wn + j * 16 + lrow;
            const float bv = bias[col];
#pragma unroll
            for (int i = 0; i < 4; ++i) {
                const int rb = bm + wm + i * 16 + quad * 4;
#pragma unroll
                for (int r = 0; r < 4; ++r) {
                    float vv = acc[i][j][r] + bv;
                    if (relu) vv = fmaxf(vv, 0.f);
                    C[(size_t)(rb + r) * N + col] = f2bu(vv);
                }
            }
        }
    }
}

// ---------------------------------------------------------------------------
// MFMA GEMM, BM=64 x BN=128, BK=32, 4 waves (2x2), wave = 32x64 via 2x4
// fragments. Counted-vmcnt 3-deep pipeline + T2 XOR swizzle + T5 setprio.
// Optional split-K as above. (Used only for the short-K O-projection.)
// ---------------------------------------------------------------------------
#define STAGE64(bi, kt) do {                                            \
        const int _k0 = (kt) * 32;                                      \
        gload16(ag + _k0,                    &As[bi][t * 8]);           \
        gload16(wg + _k0,                    &Ws[bi][t * 8]);           \
        gload16(wg + (size_t)64 * ldk + _k0, &Ws[bi][2048 + t * 8]);    \
    } while (0)

__global__ __launch_bounds__(256) void gemm64(
    const ushort* __restrict__ A, const ushort* __restrict__ W,
    const float* __restrict__ bias, ushort* __restrict__ C,
    float* __restrict__ part, int M, int N, int Kc, int ldk, int relu)
{
    __shared__ ushort As[3][64 * 32];
    __shared__ ushort Ws[3][128 * 32];

    int bxi = blockIdx.x, byi = blockIdx.y, bzi = blockIdx.z;
    xcd_swz(bxi, byi, bzi);

    const int t  = threadIdx.x;
    const int bm = byi * 64;
    const int bn = bxi * 128;
    const int z  = bzi;
    const int kbase = z * Kc;

    const int w    = t >> 6;
    const int lane = t & 63;
    const int quad = lane >> 4;
    const int lrow = lane & 15;
    const int wm   = (w >> 1) * 32;
    const int wn   = (w & 1) * 64;
    const int rx   = (lrow >> 1) & 3;
    const int rq   = (quad ^ rx) * 8;

    const int srow = t >> 2;          // 0..63
    const int scol = (((t & 3) ^ ((t >> 3) & 3)) * 8);
    const ushort* ag = A + (size_t)(bm + srow) * ldk + kbase + scol;
    const ushort* wg = W + (size_t)(bn + srow) * ldk + kbase + scol;

    f32x4 acc[2][4] = {};
    const int NT = Kc / 32;

    STAGE64(0, 0);
    STAGE64(1, 1);

    for (int kt = 0; kt < NT; ++kt) {
        if (kt + 1 < NT)
            asm volatile("s_waitcnt vmcnt(3)" ::: "memory");
        else
            asm volatile("s_waitcnt vmcnt(0)" ::: "memory");
        __builtin_amdgcn_s_barrier();

        const int cb = kt % 3;
        bf16x8 af[2], bfr[4];
#pragma unroll
        for (int i = 0; i < 2; ++i)
            af[i] = *(const bf16x8*)&As[cb][(wm + i * 16 + lrow) * 32 + rq];
#pragma unroll
        for (int j = 0; j < 4; ++j)
            bfr[j] = *(const bf16x8*)&Ws[cb][(wn + j * 16 + lrow) * 32 + rq];

        __builtin_amdgcn_s_setprio(1);
#pragma unroll
        for (int i = 0; i < 2; ++i)
#pragma unroll
            for (int j = 0; j < 4; ++j)
                acc[i][j] = __builtin_amdgcn_mfma_f32_16x16x32_bf16(
                    af[i], bfr[j], acc[i][j], 0, 0, 0);
        __builtin_amdgcn_s_setprio(0);

        if (kt + 2 < NT) {
            const int sb = (kt + 2) % 3;
            STAGE64(sb, kt + 2);
        }
    }

    if (gridDim.z > 1) {
        float* po = part + (size_t)z * M * N;
#pragma unroll
        for (int j = 0; j < 4; ++j) {
            const int col = bn + wn + j * 16 + lrow;
#pragma unroll
            for (int i = 0; i < 2; ++i) {
                const int rb = bm + wm + i * 16 + quad * 4;
#pragma unroll
                for (int r = 0; r < 4; ++r)
                    po[(size_t)(rb + r) * N + col] = acc[i][j][r];
            }
        }
    } else {
#pragma unroll
        for (int j = 0; j < 4; ++j) {
            const int col = bn + wn + j * 16 + lrow;
            const float bv = bias[col];
#pragma unroll
            for (int i = 0; i < 2; ++i) {
                const int rb = bm + wm + i * 16 + quad * 4;
#pragma unroll
                for (int r = 0; r < 4; ++r) {
                    float vv = acc[i][j][r] + bv;
                    if (relu) vv = fmaxf(vv, 0.f);
                    C[(size_t)(rb + r) * N + col] = f2bu(vv);
                }
            }
        }
    }
}

// ---------------------------------------------------------------------------
// Banded attention, flash single pass, double-buffered, swapped QK^T,
// reg-local online softmax, defer-max, mask hoisting, T5 setprio on MFMA
// clusters (m191: +4-7% on attn).
// ---------------------------------------------------------------------------
#define QT  64
#define NCH 9    // union window 64+512 = 576 keys
#define KP  72   // LDS pitch in bf16 (144 B rows: 16B-aligned, 2-way max)

__global__ __launch_bounds__(256) void attn(
    const ushort* __restrict__ q, const ushort* __restrict__ k,
    const ushort* __restrict__ v, ushort* __restrict__ o)
{
    __shared__ ushort kv[2][64][KP];   // K chunk [key][dh]
    __shared__ ushort vt[2][64][KP];   // V^T chunk [dh][key], XOR-swizzled
    __shared__ ushort sc[QT][KP];      // Q staging, then per-chunk P tiles

    int bxi = blockIdx.x, byi = blockIdx.y, bzi = blockIdx.z;
    xcd_swz(bxi, byi, bzi);            // seq-neighbors share KV -> same XCD

    const int t    = threadIdx.x;
    const int i0   = bxi * QT;
    const int h    = byi;
    const int b    = bzi;
    const size_t ibase = (size_t)b * SEQ * QKVS + (size_t)h * DH;  // q/k/v
    const size_t obase = (size_t)b * SEQ * DM   + (size_t)h * DH;  // o

    const int w    = t >> 6;
    const int lane = t & 63;
    const int quad = lane >> 4;
    const int lrow = lane & 15;
    const int qrow = w * 16;            // wave's 16 query rows

    const int jstart = i0 - HW;

    const int sjj[2] = { t >> 3, (t + 256) >> 3 };
    const int sd0 = (t & 7) * 8;

    // ---- stage Q into sc + load chunk 0 into regs -------------------------
#pragma unroll
    for (int e = 0; e < 2; ++e) {
        int idx = t + 256 * e;
        int qi = idx >> 3, d0 = (idx & 7) * 8;
        uint4 raw = *(const uint4*)(q + ibase + (size_t)(i0 + qi) * QKVS + d0);
        *(uint4*)&sc[qi][d0] = raw;
    }
    uint4 kr[2], vr[2];
#pragma unroll
    for (int e = 0; e < 2; ++e) {
        int j = jstart + sjj[e];
        kr[e] = make_uint4(0, 0, 0, 0);
        vr[e] = make_uint4(0, 0, 0, 0);
        if (j >= 0 && j < SEQ) {
            kr[e] = *(const uint4*)(k + ibase + (size_t)j * QKVS + sd0);
            vr[e] = *(const uint4*)(v + ibase + (size_t)j * QKVS + sd0);
        }
    }
#pragma unroll
    for (int e = 0; e < 2; ++e) {
        *(uint4*)&kv[0][sjj[e]][sd0] = kr[e];
        const ushort* u = (const ushort*)&vr[e];
#pragma unroll
        for (int x = 0; x < 8; ++x) {
            int dh  = sd0 + x;
            int blk = ((sjj[e] >> 3) ^ (dh >> 3)) & 7;
            vt[0][dh][blk * 8 + (sjj[e] & 7)] = u[x];
        }
    }
    __syncthreads();   // publish sc (Q) and buf0

    // Q fragments as the B-operand (chunk-invariant): B[n=lrow]=Q[qrow+lrow]
    const bf16x8 a0 = *(const bf16x8*)&sc[qrow + lrow][quad * 8];
    const bf16x8 a1 = *(const bf16x8*)&sc[qrow + lrow][32 + quad * 8];

    float m_s = -1e20f, l_s = 0.f;     // per-lane: running max/sum of q-row
    f32x4 oacc[4] = {};

    for (int c = 0; c < NCH; ++c) {
        const int cur = c & 1;
        const int j0  = jstart + c * 64;

        // ---- issue chunk c+1 global loads ---------------------------------
        if (c + 1 < NCH) {
            const int j0n = jstart + (c + 1) * 64;
#pragma unroll
            for (int e = 0; e < 2; ++e) {
                int j = j0n + sjj[e];
                kr[e] = make_uint4(0, 0, 0, 0);
                vr[e] = make_uint4(0, 0, 0, 0);
                if (j >= 0 && j < SEQ) {
                    kr[e] = *(const uint4*)(k + ibase + (size_t)j * QKVS + sd0);
                    vr[e] = *(const uint4*)(v + ibase + (size_t)j * QKVS + sd0);
                }
            }
        }

        // ---- QK^T swapped: D[m=key][n=q]; lane = 16 keys of q=qrow+lrow ---
        const bool full = (c >= 1) && (c <= 7) && (j0 >= 0) && (j0 + 64 <= SEQ);
        float p[4][4];   // [kt][r] = P[q][key = kt*16 + quad*4 + r]
#pragma unroll
        for (int kt = 0; kt < 4; ++kt) {
            const int krow = kt * 16;
            bf16x8 kf0 = *(const bf16x8*)&kv[cur][krow + lrow][quad * 8];
            bf16x8 kf1 = *(const bf16x8*)&kv[cur][krow + lrow][32 + quad * 8];
            f32x4 acc = {};
            __builtin_amdgcn_s_setprio(1);
            acc = __builtin_amdgcn_mfma_f32_16x16x32_bf16(kf0, a0, acc, 0, 0, 0);
            acc = __builtin_amdgcn_mfma_f32_16x16x32_bf16(kf1, a1, acc, 0, 0, 0);
            __builtin_amdgcn_s_setprio(0);
            if (full) {
#pragma unroll
                for (int r = 0; r < 4; ++r) p[kt][r] = acc[r] * SCALE;
            } else {
                const int ig = i0 + qrow + lrow;
#pragma unroll
                for (int r = 0; r < 4; ++r) {
                    const int jg = j0 + krow + quad * 4 + r;
                    bool ok = (jg >= 0) && (jg < SEQ) &&
                              (jg >= ig - HW) && (jg <= ig + HW);
                    p[kt][r] = ok ? acc[r] * SCALE : -1e30f;
                }
            }
        }

        // ---- online softmax: reg-local + cross-quad reduce ----------------
        float cm = p[0][0];
#pragma unroll
        for (int kt = 0; kt < 4; ++kt)
#pragma unroll
            for (int r = 0; r < 4; ++r) cm = fmaxf(cm, p[kt][r]);
        cm = fmaxf(cm, __shfl_xor(cm, 16));
        cm = fmaxf(cm, __shfl_xor(cm, 32));

        const bool resc = !__all(cm <= m_s + 8.f);   // defer-max THR=8
        float f = 1.f;
        if (resc) {
            const float mn = fmaxf(m_s, cm);
            f = __expf(m_s - mn);
            m_s = mn;
        }
        float cs = 0.f;
#pragma unroll
        for (int kt = 0; kt < 4; ++kt)
#pragma unroll
            for (int r = 0; r < 4; ++r) {
                float e = __expf(p[kt][r] - m_s);
                p[kt][r] = e;
                cs += e;
            }
        cs += __shfl_xor(cs, 16);
        cs += __shfl_xor(cs, 32);
        l_s = l_s * f + cs;
        if (resc) {
            float f4[4];
#pragma unroll
            for (int r = 0; r < 4; ++r) f4[r] = __shfl(f, quad * 4 + r);
#pragma unroll
            for (int nt = 0; nt < 4; ++nt)
#pragma unroll
                for (int r = 0; r < 4; ++r) oacc[nt][r] *= f4[r];
        }

        // ---- P to sc: 4x ushort4 at sc[q][kt*16 + quad*4] -----------------
#pragma unroll
        for (int kt = 0; kt < 4; ++kt) {
            ushort4 pw;
            pw.x = f2bu(p[kt][0]);
            pw.y = f2bu(p[kt][1]);
            pw.z = f2bu(p[kt][2]);
            pw.w = f2bu(p[kt][3]);
            *(ushort4*)&sc[qrow + lrow][kt * 16 + quad * 4] = pw;
        }

        // ---- PV: O[q][dh] += P . V^T (A-frag read unchanged) --------------
        bf16x8 pa0 = *(const bf16x8*)&sc[qrow + lrow][quad * 8];
        bf16x8 pa1 = *(const bf16x8*)&sc[qrow + lrow][32 + quad * 8];
        __builtin_amdgcn_s_setprio(1);
#pragma unroll
        for (int nt = 0; nt < 4; ++nt) {
            const int dh  = nt * 16 + lrow;
            const int rsw = (dh >> 3) & 7;
            bf16x8 b0 = *(const bf16x8*)&vt[cur][dh][((quad)     ^ rsw) * 8];
            bf16x8 b1 = *(const bf16x8*)&vt[cur][dh][((quad + 4) ^ rsw) * 8];
            oacc[nt] = __builtin_amdgcn_mfma_f32_16x16x32_bf16(pa0, b0, oacc[nt], 0, 0, 0);
            oacc[nt] = __builtin_amdgcn_mfma_f32_16x16x32_bf16(pa1, b1, oacc[nt], 0, 0, 0);
        }
        __builtin_amdgcn_s_setprio(0);

        // ---- write chunk c+1 regs to buf[cur^1] ---------------------------
        if (c + 1 < NCH) {
            const int nxt = cur ^ 1;
#pragma unroll
            for (int e = 0; e < 2; ++e) {
                *(uint4*)&kv[nxt][sjj[e]][sd0] = kr[e];
                const ushort* u = (const ushort*)&vr[e];
#pragma unroll
                for (int x = 0; x < 8; ++x) {
                    int dh  = sd0 + x;
                    int blk = ((sjj[e] >> 3) ^ (dh >> 3)) & 7;
                    vt[nxt][dh][blk * 8 + (sjj[e] & 7)] = u[x];
                }
            }
        }
        __syncthreads();   // single barrier: publishes buf[nxt], drains buf[cur]
    }

    // ---- write O: col(dh) = nt*16 + lrow, row(q) = qrow + quad*4 + r ------
    const float inv = 1.f / l_s;          // lane's q-row = qrow + lrow
    float inv4[4];
#pragma unroll
    for (int r = 0; r < 4; ++r) inv4[r] = __shfl(inv, quad * 4 + r);
#pragma unroll
    for (int r = 0; r < 4; ++r) {
        const int qi = i0 + qrow + quad * 4 + r;
#pragma unroll
        for (int nt = 0; nt < 4; ++nt)
            o[obase + (size_t)qi * DM + nt * 16 + lrow] = f2bu(oacc[nt][r] * inv4[r]);
    }
}

// ---------------------------------------------------------------------------
// Fused split-K reduce (2 planes) + residual + LayerNorm (O-proj tail).
// ---------------------------------------------------------------------------
__global__ __launch_bounds__(256) void add_ln_sk(
    const ushort* __restrict__ xa, const float* __restrict__ pp,
    const float* __restrict__ bias, const float* __restrict__ g,
    const float* __restrict__ be,
    ushort* __restrict__ ob, float* __restrict__ of, int fin)
{
    const int r = blockIdx.x * 4 + (threadIdx.x >> 6);
    const int t = threadIdx.x & 63;
    const size_t off = (size_t)r * DM;
    const size_t pl  = (size_t)MR * DM;
    float sv[12];
    float s1 = 0.f, s2 = 0.f;
#pragma unroll
    for (int ii = 0; ii < 12; ++ii) {
        const int c = t + 64 * ii;
        float vv = bu2f(xa[off + c]) + pp[off + c] + pp[pl + off + c] + bias[c];
        sv[ii] = vv; s1 += vv; s2 += vv * vv;
    }
#pragma unroll
    for (int o2 = 32; o2; o2 >>= 1) {
        s1 += __shfl_xor(s1, o2);
        s2 += __shfl_xor(s2, o2);
    }
    const float mean = s1 * (1.f / 768.f);
    const float rstd = rsqrtf(s2 * (1.f / 768.f) - mean * mean + EPSF);
#pragma unroll
    for (int ii = 0; ii < 12; ++ii) {
        const int c = t + 64 * ii;
        float v = (sv[ii] - mean) * rstd * g[c] + be[c];
        if (fin) of[off + c] = v;
        else     ob[off + c] = f2bu(v);
    }
}

// ---------------------------------------------------------------------------
// Fused split-K reduce (3 planes) + residual + LayerNorm (FF2 tail).
// ---------------------------------------------------------------------------
__global__ __launch_bounds__(256) void add_ln_sk3(
    const ushort* __restrict__ xa, const float* __restrict__ pp,
    const float* __restrict__ bias, const float* __restrict__ g,
    const float* __restrict__ be,
    ushort* __restrict__ ob, float* __restrict__ of, int fin)
{
    const int r = blockIdx.x * 4 + (threadIdx.x >> 6);
    const int t = threadIdx.x & 63;
    const size_t off = (size_t)r * DM;
    const size_t pl  = (size_t)MR * DM;
    float sv[12];
    float s1 = 0.f, s2 = 0.f;
#pragma unroll
    for (int ii = 0; ii < 12; ++ii) {
        const int c = t + 64 * ii;
        float vv = bu2f(xa[off + c]) + pp[off + c] + pp[pl + off + c]
                 + pp[2 * pl + off + c] + bias[c];
        sv[ii] = vv; s1 += vv; s2 += vv * vv;
    }
#pragma unroll
    for (int o2 = 32; o2; o2 >>= 1) {
        s1 += __shfl_xor(s1, o2);
        s2 += __shfl_xor(s2, o2);
    }
    const float mean = s1 * (1.f / 768.f);
    const float rstd = rsqrtf(s2 * (1.f / 768.f) - mean * mean + EPSF);
#pragma unroll
    for (int ii = 0; ii < 12; ++ii) {
        const int c = t + 64 * ii;
        float v = (sv[ii] - mean) * rstd * g[c] + be[c];
        if (fin) of[off + c] = v;
        else     ob[off + c] = f2bu(v);
    }
}

// ---------------------------------------------------------------------------
// Host orchestration.
// Buffer lifetime plan (x alternates xb -> x2 so partial regions are dead):
//   partF (FF2, 3 fp32 planes = 6A ushorts) = contiguous [xb..yB]
//   partO (O-proj, 2 fp32 planes = 4A ushorts) = ffh
// ---------------------------------------------------------------------------
extern "C" void kernel_launch(void* const* d_in, const int* in_sizes, int n_in,
                              void* d_out, int out_size, void* d_ws, size_t ws_size,
                              hipStream_t stream) {
    (void)in_sizes; (void)n_in; (void)out_size; (void)ws_size;
    const float* src = (const float*)d_in[0];
    const float* qw  = (const float*)d_in[1];
    const float* qb  = (const float*)d_in[2];
    const float* kw  = (const float*)d_in[3];
    const float* kb  = (const float*)d_in[4];
    const float* vw  = (const float*)d_in[5];
    const float* vb  = (const float*)d_in[6];
    const float* ow  = (const float*)d_in[7];
    const float* ob  = (const float*)d_in[8];
    const float* w1  = (const float*)d_in[9];
    const float* b1  = (const float*)d_in[10];
    const float* w2  = (const float*)d_in[11];
    const float* b2  = (const float*)d_in[12];
    const float* g1  = (const float*)d_in[13];
    const float* be1 = (const float*)d_in[14];
    const float* g2  = (const float*)d_in[15];
    const float* be2 = (const float*)d_in[16];

    const size_t A    = (size_t)MR * DM;         // 3,145,728
    const size_t WD1  = (size_t)DM * DM;         // 589,824  (per layer)
    const size_t WQKV = (size_t)3 * DM * DM;     // 1,769,472 (per layer)
    const size_t WF1  = (size_t)DFF * DM;        // 2,359,296 (per layer)
    const size_t WF   = (size_t)NL * WF1;        // 4,718,592

    float*  bcat = (float*)d_ws;                 // NL * 2304 fp32
    ushort* p    = (ushort*)(bcat + (size_t)NL * QKVS);
    ushort* qkvwB = p; p += (size_t)NL * WQKV;
    ushort* owB   = p; p += (size_t)NL * WD1;
    ushort* w1B   = p; p += WF;
    ushort* w2B   = p; p += WF;
    ushort* xb    = p; p += A;       // x (layer 0) / FF2 partial plane 0
    ushort* qkvB  = p; p += 3 * A;   // qkv          / FF2 partials
    ushort* oB    = p; p += A;       // attn out     / FF2 partials
    ushort* yB    = p; p += A;       // (dead)       / FF2 partials
    ushort* h1    = p; p += A;       // post-LN1 residual
    ushort* ffh   = p; p += 4 * A;   // FF1 out (4A = MR*DFF) / O-proj partials
    ushort* x2    = p;               // x (layer 1)

    float* partF = (float*)xb;       // 3 planes: [xb..yB] = 6A ushorts
    float* partO = (float*)ffh;      // 2 planes: 4A ushorts

    // bias concat + weight/src conversion (launch-consolidated: 7 nodes)
    bias_cat<<<NL * 3, 256, 0, stream>>>(qb, kb, vb, bcat);
    {
        dim3 g3((int)(3 * WD1 / 1024), NL);
        cvt3<<<g3, 256, 0, stream>>>(qw, kw, vw, qkvwB, (int)WD1, (int)WQKV);
    }
    cvt<<<(int)(NL * WD1 / 1024), 256, 0, stream>>>(ow, owB, (int)(NL * WD1));
    cvt<<<(int)(WF / 1024), 256, 0, stream>>>(w1, w1B, (int)WF);
    cvt<<<(int)(WF / 1024), 256, 0, stream>>>(w2, w2B, (int)WF);
    cvt<<<(int)(A  / 1024), 256, 0, stream>>>(src, xb, (int)A);

    const dim3 gQKV(QKVS / 128, MR / 128);      // (18, 32)  576 blocks
    const dim3 gOp(DM / 128, MR / 64, 2);       // (6, 64, 2) 768 blocks
    const dim3 gF1(DFF / 128, MR / 128);        // (24, 32)  768 blocks
    const dim3 gF2(DM / 128, MR / 128, 3);      // (6, 32, 3) 576 blocks
    const dim3 gA(SEQ / QT, NHD, BATCH);        // (32, 12, 2) 768 blocks

    for (int l = 0; l < NL; ++l) {
        const size_t bD = (size_t)l * DM;
        const size_t bF = (size_t)l * DFF;
        const ushort* xin = (l == 0) ? xb : x2;

        gemm128<<<gQKV, 256, 0, stream>>>(xin, qkvwB + (size_t)l * WQKV,
                                          bcat + (size_t)l * QKVS, qkvB,
                                          nullptr, MR, QKVS, DM, DM, 0);
        attn<<<gA, 256, 0, stream>>>(qkvB, qkvB + DM, qkvB + 2 * DM, oB);
        // O-proj split-K: K=768 -> 2 chunks of 384; fp32 partials in ffh
        gemm64<<<gOp, 256, 0, stream>>>(oB, owB + (size_t)l * WD1, nullptr,
                                        nullptr, partO, MR, DM, DM / 2, DM, 0);
        add_ln_sk<<<MR / 4, 256, 0, stream>>>(xin, partO, ob + bD,
                                              g1 + bD, be1 + bD,
                                              h1, nullptr, 0);
        gemm128<<<gF1, 256, 0, stream>>>(h1, w1B + (size_t)l * WF1, b1 + bF, ffh,
                                         nullptr, MR, DFF, DM, DM, 1);
        // FF2 split-K: K=3072 -> 3 chunks of 1024; fp32 partials in [xb..yB]
        gemm128<<<gF2, 256, 0, stream>>>(ffh, w2B + (size_t)l * WF1, nullptr,
                                         nullptr, partF, MR, DM, DFF / 3, DFF, 0);
        if (l == NL - 1)
            add_ln_sk3<<<MR / 4, 256, 0, stream>>>(h1, partF, b2 + bD,
                                                   g2 + bD, be2 + bD,
                                                   nullptr, (float*)d_out, 1);
        else
            add_ln_sk3<<<MR / 4, 256, 0, stream>>>(h1, partF, b2 + bD,
                                                   g2 + bD, be2 + bD,
                                                   x2, nullptr, 0);
    }
}